// Round 2
// baseline (342.606 us; speedup 1.0000x reference)
//
#include <hip/hip_runtime.h>

typedef __bf16 bf16;
typedef __bf16 bf16x8 __attribute__((ext_vector_type(8)));
typedef __bf16 bf16x4 __attribute__((ext_vector_type(4)));
typedef float floatx4 __attribute__((ext_vector_type(4)));
typedef int   intx4  __attribute__((ext_vector_type(4)));
typedef int   intx2  __attribute__((ext_vector_type(2)));

#define MFMA16(a,b,c) __builtin_amdgcn_mfma_f32_16x16x32_bf16((a),(b),(c),0,0,0)

constexpr int Bc  = 4;
constexpr int Sc  = 2048;
constexpr int Hc  = 1024;
constexpr int NHc = 16;
constexpr int HDc = 64;
constexpr int Mc  = Bc * Sc;       // 8192 rows
constexpr int KIT = Hc / 32;       // 32 k-iterations
constexpr float L2E = 1.44269504088896f;

union U64  { bf16x4 h; intx2 i; };

// async global->LDS, 16B per lane (dest must be wave-uniform base + lane*16)
__device__ __forceinline__ void ld16(const bf16* g, bf16* l) {
    __builtin_amdgcn_global_load_lds(
        (const __attribute__((address_space(1))) void*)g,
        (__attribute__((address_space(3))) void*)l, 16, 0, 0);
}

// ---------------------------------------------------------------------------
// dtype detection (flag=1 -> inputs are fp32)
// ---------------------------------------------------------------------------
__global__ void detect_k(const unsigned short* __restrict__ x, int* __restrict__ flag)
{
    if (threadIdx.x == 0 && blockIdx.x == 0) {
        float mx = 0.f;
        for (int i = 0; i < 256; ++i) {
            unsigned int bits = ((unsigned int)x[i]) << 16;
            float v = __uint_as_float(bits);
            if (!isfinite(v)) { mx = 1e30f; break; }
            mx = fmaxf(mx, fabsf(v));
        }
        *flag = (mx > 1e6f) ? 1 : 0;
    }
}

// ---------------------------------------------------------------------------
// One merged conversion kernel: x (1048576 g8) | 4 weights (524288 g8) |
// mask+6 vectors (1792 g8)
// ---------------------------------------------------------------------------
__global__ __launch_bounds__(256)
void conv_all_k(const void* __restrict__ x,
                const void* __restrict__ Wq, const void* __restrict__ Wk,
                const void* __restrict__ Wv, const void* __restrict__ Wo,
                const void* __restrict__ mask,
                const void* __restrict__ bq, const void* __restrict__ bk,
                const void* __restrict__ bv, const void* __restrict__ bo,
                const void* __restrict__ lnw, const void* __restrict__ lnb,
                bf16* __restrict__ xb, bf16* __restrict__ wdst,
                float* maskf, float* bqf, float* bkf, float* bvf,
                float* bof, float* lnwf, float* lnbf,
                const int* __restrict__ flag)
{
    const int g = blockIdx.x * 256 + threadIdx.x;
    const int fl = *flag;
    if (g < 1048576) {
        if (fl) {
            const float* s = (const float*)x + (size_t)g * 8;
            union { intx4 v; bf16 e[8]; } o;
#pragma unroll
            for (int j = 0; j < 8; ++j) o.e[j] = (bf16)s[j];
            *(intx4*)(xb + (size_t)g * 8) = o.v;
        } else {
            *(intx4*)(xb + (size_t)g * 8) = *((const intx4*)x + g);
        }
    } else if (g < 1048576 + 524288) {
        const int gw = g - 1048576;
        const int wsel = gw >> 17, go = gw & 131071;
        const void* s = (wsel == 0) ? Wq : (wsel == 1) ? Wk : (wsel == 2) ? Wv : Wo;
        if (fl) {
            const float* sp = (const float*)s + (size_t)go * 8;
            union { intx4 v; bf16 e[8]; } o;
#pragma unroll
            for (int j = 0; j < 8; ++j) o.e[j] = (bf16)sp[j];
            *(intx4*)(wdst + (size_t)gw * 8) = o.v;
        } else {
            *(intx4*)(wdst + (size_t)gw * 8) = *((const intx4*)s + go);
        }
    } else {
        const int gs = g - 1048576 - 524288;
        if (gs >= 1792) return;
        const void* src; float* dst; int off; float scl = 1.0f;
        if (gs < 1024) { src = mask; dst = maskf; off = gs * 8; scl = L2E; }
        else {
            const int a = (gs - 1024) >> 7;
            off = ((gs - 1024) & 127) * 8;
            switch (a) {
                case 0: src = bq;  dst = bqf;  break;
                case 1: src = bk;  dst = bkf;  break;
                case 2: src = bv;  dst = bvf;  break;
                case 3: src = bo;  dst = bof;  break;
                case 4: src = lnw; dst = lnwf; break;
                default: src = lnb; dst = lnbf; break;
            }
        }
        if (fl) {
            const float* s = (const float*)src + off;
#pragma unroll
            for (int j = 0; j < 8; ++j) dst[off + j] = s[j] * scl;
        } else {
            union { intx4 v; bf16 e[8]; } u;
            u.v = *(const intx4*)((const bf16*)src + off);
#pragma unroll
            for (int j = 0; j < 8; ++j) dst[off + j] = (float)u.e[j] * scl;
        }
    }
}

// ---------------------------------------------------------------------------
// GEMM core (m97 structure): 128x128 tile over K=1024, A/W both row-major.
// SWAP=0: acc[i][j] = C[xrow-block i][feat-block j]
// SWAP=1: acc[i][j] = C[feat-block j][xrow-block i] (lane cols = xrow)
// ---------------------------------------------------------------------------
template<int SWAP>
__device__ __forceinline__
void gemm_core(const bf16* __restrict__ A, const bf16* __restrict__ W,
               int m0, int n0, int t, bf16* As, bf16* Bs, floatx4 (&acc)[4][4])
{
    const int l  = t & 63, w = t >> 6;
    const int wr = w >> 1, wc = w & 1;
    const int lq = l >> 4, ln = l & 15;
    const int srow = t >> 2;            // 0..63
    const int scol = (t & 3) * 8;       // 0,8,16,24

    const bf16* a0 = A + (size_t)(m0 + srow) * Hc + scol;
    const bf16* b0 = W + (size_t)(n0 + srow) * Hc + scol;
    bf16* lA0 = As + srow * 32 + scol;    // lane-linear
    bf16* lA1 = lA0 + 64 * 32;
    bf16* lB0 = Bs + srow * 32 + scol;
    bf16* lB1 = lB0 + 64 * 32;

    for (int kb = 0; kb < KIT; ++kb) {
        const int off = kb * 32;
        ld16(a0 + off,           lA0);
        ld16(a0 + 64 * Hc + off, lA1);
        ld16(b0 + off,           lB0);
        ld16(b0 + 64 * Hc + off, lB1);
        __syncthreads();

        bf16x8 af[4], bw[4];
#pragma unroll
        for (int i = 0; i < 4; ++i)
            af[i] = *(const bf16x8*)&As[(wr * 64 + i * 16 + ln) * 32 + lq * 8];
#pragma unroll
        for (int j = 0; j < 4; ++j)
            bw[j] = *(const bf16x8*)&Bs[(wc * 64 + j * 16 + ln) * 32 + lq * 8];
#pragma unroll
        for (int i = 0; i < 4; ++i)
#pragma unroll
            for (int j = 0; j < 4; ++j)
                acc[i][j] = SWAP ? MFMA16(bw[j], af[i], acc[i][j])
                                 : MFMA16(af[i], bw[j], acc[i][j]);
        __syncthreads();
    }
}

// ---------------------------------------------------------------------------
// Fused QKV: z=0 -> q (scaled by 0.125*log2e) [B,NH,S,HD]; z=1 -> k;
// z=2 -> V^T [B,NH,HD,S] via LDS transpose
// ---------------------------------------------------------------------------
__global__ __launch_bounds__(256)
void qkv_gemm(const bf16* __restrict__ x,
              const bf16* __restrict__ Wq, const float* __restrict__ bq,
              const bf16* __restrict__ Wk, const float* __restrict__ bk,
              const bf16* __restrict__ Wv, const float* __restrict__ bv,
              bf16* __restrict__ qo, bf16* __restrict__ ko, bf16* __restrict__ vto)
{
    __shared__ __align__(16) bf16 smem[8704];   // max(2*128*32, 64*136)
    const int z = blockIdx.z;
    const bf16*  W    = (z == 0) ? Wq : (z == 1) ? Wk : Wv;
    const float* bias = (z == 0) ? bq : (z == 1) ? bk : bv;

    const int m0 = blockIdx.y * 128, n0 = blockIdx.x * 128;
    const int t  = threadIdx.x;
    const int l  = t & 63, w = t >> 6;
    const int wr = w >> 1, wc = w & 1;
    const int lq = l >> 4, ln = l & 15;

    if (z < 2) {
        floatx4 acc[4][4] = {};
        gemm_core<1>(x, W, m0, n0, t, smem, smem + 4096, acc);
        bf16* out = (z == 0) ? qo : ko;
        const float sc = (z == 0) ? 0.125f * L2E : 1.0f;
#pragma unroll
        for (int j = 0; j < 4; ++j) {
            const int feat = n0 + wc * 64 + j * 16 + lq * 4;   // 4 consecutive
            const floatx4 bb = *(const floatx4*)&bias[feat];
            const int hh = feat >> 6, dd = feat & 63;
#pragma unroll
            for (int i = 0; i < 4; ++i) {
                const int xrow = m0 + wr * 64 + i * 16 + ln;
                const int bi = xrow >> 11, si = xrow & (Sc - 1);
                U64 pk;
#pragma unroll
                for (int r = 0; r < 4; ++r) pk.h[r] = (bf16)((acc[i][j][r] + bb[r]) * sc);
                *(intx2*)&out[(((size_t)bi * NHc + hh) * Sc + si) * HDc + dd] = pk.i;
            }
        }
    } else {
        floatx4 acc[4][4] = {};
        gemm_core<0>(x, W, m0, n0, t, smem, smem + 4096, acc);
        // transpose epilogue: Ct[64 cols][136 rows], two col-halves
        bf16* Ct = smem;
        const int bi = m0 >> 11, s0 = m0 & (Sc - 1);
        for (int h2 = 0; h2 < 2; ++h2) {
            __syncthreads();
            if (wc == h2) {
#pragma unroll
                for (int j = 0; j < 4; ++j) {
                    const int c = j * 16 + ln;
                    const float bb = bias[n0 + h2 * 64 + c];
#pragma unroll
                    for (int i = 0; i < 4; ++i) {
                        U64 pk;
#pragma unroll
                        for (int r = 0; r < 4; ++r) pk.h[r] = (bf16)(acc[i][j][r] + bb);
                        *(intx2*)&Ct[c * 136 + wr * 64 + i * 16 + lq * 4] = pk.i;
                    }
                }
            }
            __syncthreads();
#pragma unroll
            for (int u = 0; u < 4; ++u) {
                const int id = t + 256 * u;           // 0..1023
                const int c = id >> 4, rg = id & 15;
                const int hh = (n0 >> 6) + h2;
                intx4 val = *(const intx4*)&Ct[c * 136 + rg * 8];
                *(intx4*)&vto[(((size_t)bi * NHc + hh) * HDc + c) * Sc + s0 + rg * 8] = val;
            }
        }
    }
}

// ---------------------------------------------------------------------------
// Output projection + bias + residual -> h (bf16), b64 loads/stores
// ---------------------------------------------------------------------------
__global__ __launch_bounds__(256)
void oproj_gemm(const bf16* __restrict__ ctx, const bf16* __restrict__ Wo,
                const float* __restrict__ bo, const bf16* __restrict__ xb,
                bf16* __restrict__ hout)
{
    __shared__ __align__(16) bf16 smem[8192];
    const int m0 = blockIdx.y * 128, n0 = blockIdx.x * 128;
    const int t  = threadIdx.x;
    floatx4 acc[4][4] = {};
    gemm_core<1>(ctx, Wo, m0, n0, t, smem, smem + 4096, acc);

    const int l  = t & 63, w = t >> 6;
    const int wr = w >> 1, wc = w & 1;
    const int lq = l >> 4, ln = l & 15;
#pragma unroll
    for (int j = 0; j < 4; ++j) {
        const int col = n0 + wc * 64 + j * 16 + lq * 4;   // 4 consecutive
        const floatx4 bb = *(const floatx4*)&bo[col];
#pragma unroll
        for (int i = 0; i < 4; ++i) {
            const int row = m0 + wr * 64 + i * 16 + ln;
            U64 rx;
            rx.i = *(const intx2*)&xb[(size_t)row * Hc + col];
            U64 pk;
#pragma unroll
            for (int r = 0; r < 4; ++r)
                pk.h[r] = (bf16)(acc[i][j][r] + bb[r] + (float)rx.h[r]);
            *(intx2*)&hout[(size_t)row * Hc + col] = pk.i;
        }
    }
}

// ---------------------------------------------------------------------------
// Flash attention, S^T formulation, fixed-max softmax.
// 1 WG = 4 waves x 64 q-rows = 256 q-rows; K-tiles of 64.
// LDS-pipe-optimized: K/V staged via global_load_lds DMA into a double
// buffer (XOR-swizzled via pre-swizzled global source, linear DMA dest),
// ONE barrier per tile, and the P^T round-trip through LDS replaced by an
// in-register 4-lane transpose (v_permlane32/16_swap) -> zero Pt traffic.
// Softmax denominator: f32 adds + 2 final shfl_xor (no ones-MFMA).
// ---------------------------------------------------------------------------
__global__ __launch_bounds__(256, 2)
void attention(const bf16* __restrict__ q, const bf16* __restrict__ k,
               const bf16* __restrict__ vt, const float* __restrict__ maskf,
               bf16* __restrict__ ctx)
{
    __shared__ __align__(16) bf16 KV[2][2][64][64];   // [dbuf][K|V][row][col] 32 KB

    // XCD-aware remap: raw%8 = XCD; 8 consecutive (b,h) per XCD so each
    // K/V panel is fetched by ONE L2. 512 % 8 == 0 -> bijective.
    const int raw = blockIdx.x;                 // 0..511
    const int xcd = raw & 7, jj = raw >> 3;     // jj 0..63
    const int bh  = xcd * 8 + (jj >> 3);
    const int qt  = jj & 7;                     // q-tile of 256 rows
    const int b = bh >> 4, h = bh & 15;
    const int t = threadIdx.x, w = t >> 6, l = t & 63;
    const int lq = l >> 4, ln = l & 15;
    const int q0 = qt * 256 + w * 64;

    const bf16* kg = k  + (size_t)bh * Sc * HDc;
    const bf16* vg = vt + (size_t)bh * HDc * Sc;
    const float* mbase = maskf + b * Sc;        // pre-scaled by log2e

    // DMA staging geometry: wave w covers rows [16w,16w+16) of the 64-row
    // tile in two 8-row calls; lane l -> row +(l>>3), column granule (l&7).
    // Swizzle: LDS granule c of row r holds global granule c ^ (r&7).
    const int rr  = l >> 3;
    const int gsw = ((l & 7) ^ rr) << 3;        // global column offset (elems)
    const int r0  = w * 16 + rr, r1 = r0 + 8;
    const int dco = (l & 7) << 3;               // linear LDS column (elems)

    // Q fragments in registers (B-operand); q pre-scaled by 0.125*log2e
    bf16x8 qf[4][2];
#pragma unroll
    for (int qb = 0; qb < 4; ++qb)
#pragma unroll
        for (int kh = 0; kh < 2; ++kh)
            qf[qb][kh] = *(const bf16x8*)(q + ((size_t)bh * Sc + q0 + qb * 16 + ln) * HDc
                                            + kh * 32 + lq * 8);

    floatx4 o[4][4] = {};
    float dacc[4] = {0.f, 0.f, 0.f, 0.f};

    auto stage = [&](int buf, int kt) {
        bf16* Kd = &KV[buf][0][0][0];
        bf16* Vd = &KV[buf][1][0][0];
        ld16(kg + (size_t)(kt * 64 + r0) * HDc + gsw, Kd + r0 * 64 + dco);
        ld16(kg + (size_t)(kt * 64 + r1) * HDc + gsw, Kd + r1 * 64 + dco);
        ld16(vg + (size_t)r0 * Sc + kt * 64 + gsw,    Vd + r0 * 64 + dco);
        ld16(vg + (size_t)r1 * Sc + kt * 64 + gsw,    Vd + r1 * 64 + dco);
    };

    stage(0, 0);
    int cur = 0;

    for (int kt = 0; kt < Sc / 64; ++kt) {
        __syncthreads();                 // drains own vmcnt -> buf[cur] ready
        if (kt + 1 < Sc / 64) stage(cur ^ 1, kt + 1);

        const bf16* Kb = &KV[cur][0][0][0];
        const bf16* Vb = &KV[cur][1][0][0];

        // mask (log2 domain): becomes the QK^T accumulator init (free add)
        floatx4 mvl[4];
#pragma unroll
        for (int cb = 0; cb < 4; ++cb)
            mvl[cb] = *(const floatx4*)(mbase + kt * 64 + cb * 16 + lq * 4);

        // K & V fragments once per tile (shared across all 4 q-blocks),
        // swizzled reads -> uniform 8 lanes/bank-quad (conflict-free b128)
        bf16x8 kf[4][2], vf[4][2];
        const int sw = ln & 7;
#pragma unroll
        for (int cb = 0; cb < 4; ++cb) {
            const int row = (cb * 16 + ln) * 64;
#pragma unroll
            for (int kh = 0; kh < 2; ++kh) {
                const int cc = ((kh * 4 + lq) ^ sw) << 3;
                kf[cb][kh] = *(const bf16x8*)&Kb[row + cc];
                vf[cb][kh] = *(const bf16x8*)&Vb[row + cc];
            }
        }

        __builtin_amdgcn_s_setprio(1);
#pragma unroll
        for (int qb = 0; qb < 4; ++qb) {
            // S^T = K*Q^T + mask  (lane holds kpos 16cb+4lq+r for qrow ln)
            floatx4 s[4];
#pragma unroll
            for (int cb = 0; cb < 4; ++cb) {
                s[cb] = mvl[cb];
                s[cb] = MFMA16(kf[cb][0], qf[qb][0], s[cb]);
                s[cb] = MFMA16(kf[cb][1], qf[qb][1], s[cb]);
            }
            // p = exp2(s); pack to bf16 pairs; accumulate denom in f32
            unsigned int D[4][2];
            float ds = 0.f;
#pragma unroll
            for (int cb = 0; cb < 4; ++cb)
#pragma unroll
                for (int i = 0; i < 2; ++i) {
                    const float e0 = __builtin_amdgcn_exp2f(s[cb][2 * i]);
                    const float e1 = __builtin_amdgcn_exp2f(s[cb][2 * i + 1]);
                    ds += e0 + e1;
                    union { unsigned int u; bf16 e[2]; } pk2;
                    pk2.e[0] = (bf16)e0; pk2.e[1] = (bf16)e1;
                    D[cb][i] = pk2.u;
                }
            dacc[qb] += ds;

            // in-register P^T redistribution: 4-lane transpose over lanes
            // {l, l+16, l+32, l+48}: permlane32_swap then permlane16_swap
            // turns (D[c][i]@src, D[c+1][i]@src) into PV B-fragment dwords.
            unsigned int F0[4], F1[4];
            {
                unsigned int A, B;
                A = D[0][0]; B = D[1][0];
                asm("v_permlane32_swap_b32 %0, %1" : "+v"(A), "+v"(B));
                asm("v_permlane16_swap_b32 %0, %1" : "+v"(A), "+v"(B));
                F0[0] = A; F0[2] = B;
                A = D[0][1]; B = D[1][1];
                asm("v_permlane32_swap_b32 %0, %1" : "+v"(A), "+v"(B));
                asm("v_permlane16_swap_b32 %0, %1" : "+v"(A), "+v"(B));
                F0[1] = A; F0[3] = B;
                A = D[2][0]; B = D[3][0];
                asm("v_permlane32_swap_b32 %0, %1" : "+v"(A), "+v"(B));
                asm("v_permlane16_swap_b32 %0, %1" : "+v"(A), "+v"(B));
                F1[0] = A; F1[2] = B;
                A = D[2][1]; B = D[3][1];
                asm("v_permlane32_swap_b32 %0, %1" : "+v"(A), "+v"(B));
                asm("v_permlane16_swap_b32 %0, %1" : "+v"(A), "+v"(B));
                F1[1] = A; F1[3] = B;
            }
            union { unsigned int u[4]; bf16x8 v; } P0, P1;
#pragma unroll
            for (int d = 0; d < 4; ++d) { P0.u[d] = F0[d]; P1.u[d] = F1[d]; }
            const bf16x8 pf0 = P0.v, pf1 = P1.v;

            // O^T += V^T * P^T
#pragma unroll
            for (int db = 0; db < 4; ++db) {
                o[qb][db] = MFMA16(vf[db][0], pf0, o[qb][db]);
                o[qb][db] = MFMA16(vf[db][1], pf1, o[qb][db]);
            }
        }
        __builtin_amdgcn_s_setprio(0);
        cur ^= 1;
    }

    // finish denominators (sum over the 4-lane stride-16 group), store ctx
#pragma unroll
    for (int qb = 0; qb < 4; ++qb) {
        float dsum = dacc[qb];
        dsum += __shfl_xor(dsum, 16, 64);
        dsum += __shfl_xor(dsum, 32, 64);
        const float li = 1.f / dsum;
        const int qg = q0 + qb * 16 + ln;
#pragma unroll
        for (int db = 0; db < 4; ++db) {
            U64 pk;
#pragma unroll
            for (int r = 0; r < 4; ++r) pk.h[r] = (bf16)(o[qb][db][r] * li);
            *(intx2*)&ctx[((size_t)b * Sc + qg) * Hc + h * HDc + db * 16 + lq * 4] = pk.i;
        }
    }
}

// ---------------------------------------------------------------------------
// LayerNorm; output dtype keyed off flag
// ---------------------------------------------------------------------------
__global__ __launch_bounds__(256)
void layernorm_k(const bf16* __restrict__ hbuf, const float* __restrict__ lw,
                 const float* __restrict__ lb, void* __restrict__ outp,
                 const int* __restrict__ flag)
{
    const int row = blockIdx.x;
    const int t = threadIdx.x;
    const bf16* hp = hbuf + (size_t)row * Hc;

    union { intx2 i2; bf16 e[4]; } pk;
    pk.i2 = *(const intx2*)(hp + t * 4);
    float v[4], sum = 0.f, sq = 0.f;
#pragma unroll
    for (int i = 0; i < 4; ++i) {
        v[i] = (float)pk.e[i];
        sum += v[i];
        sq  += v[i] * v[i];
    }
#pragma unroll
    for (int off = 1; off < 64; off <<= 1) {
        sum += __shfl_xor(sum, off, 64);
        sq  += __shfl_xor(sq,  off, 64);
    }
    __shared__ float ssum[4], ssq[4];
    const int w = t >> 6;
    if ((t & 63) == 0) { ssum[w] = sum; ssq[w] = sq; }
    __syncthreads();
    sum = ssum[0] + ssum[1] + ssum[2] + ssum[3];
    sq  = ssq[0]  + ssq[1]  + ssq[2]  + ssq[3];

    const float mean = sum * (1.f / (float)Hc);
    const float var  = sq * (1.f / (float)Hc) - mean * mean;
    const float rstd = rsqrtf(var + 1e-12f);

    float ov[4];
#pragma unroll
    for (int i = 0; i < 4; ++i) {
        const int c = t * 4 + i;
        ov[i] = lw[c] * (v[i] - mean) * rstd + lb[c];
    }
    if (*flag) {
        float* of = (float*)outp + (size_t)row * Hc + t * 4;
#pragma unroll
        for (int i = 0; i < 4; ++i) of[i] = ov[i];
    } else {
        union { intx2 i2; bf16 e[4]; } po;
#pragma unroll
        for (int i = 0; i < 4; ++i) po.e[i] = (bf16)ov[i];
        *(intx2*)((bf16*)outp + (size_t)row * Hc + t * 4) = po.i2;
    }
}

// ---------------------------------------------------------------------------
extern "C" void kernel_launch(void* const* d_in, const int* in_sizes, int n_in,
                              void* d_out, int out_size, void* d_ws, size_t ws_size,
                              hipStream_t stream)
{
    const void* x    = d_in[0];
    const void* mask = d_in[1];
    const void* Wq   = d_in[2];
    const void* bq   = d_in[3];
    const void* Wk   = d_in[4];
    const void* bk   = d_in[5];
    const void* Wv   = d_in[6];
    const void* bv   = d_in[7];
    const void* Wo   = d_in[8];
    const void* bo   = d_in[9];
    const void* lnw  = d_in[10];
    const void* lnb  = d_in[11];

    char* ws = (char*)d_ws;
    const size_t MB = 1024 * 1024;
    int*   flag  = (int*)ws;
    float* maskf = (float*)(ws + 4096);
    float* bqf   = (float*)(ws + 64 * 1024);
    float* bkf   = bqf + Hc;
    float* bvf   = bkf + Hc;
    float* bof   = bvf + Hc;
    float* lnwf  = bof + Hc;
    float* lnbf  = lnwf + Hc;
    bf16* xb  = (bf16*)(ws + 1 * MB);    // 16 MB
    bf16* wqb = (bf16*)(ws + 17 * MB);   // 2 MB each, contiguous wq|wk|wv|wo
    bf16* wkb = (bf16*)(ws + 19 * MB);
    bf16* wvb = (bf16*)(ws + 21 * MB);
    bf16* wob = (bf16*)(ws + 23 * MB);
    bf16* qb  = (bf16*)(ws + 25 * MB);   // 16 MB
    bf16* kb  = (bf16*)(ws + 41 * MB);
    bf16* vtb = (bf16*)(ws + 57 * MB);   // V^T
    bf16* cb  = (bf16*)(ws + 73 * MB);   // ctx; high water 89 MB
    bf16* hb  = qb;                      // h reuses q (dead after attention)

    detect_k<<<1, 64, 0, stream>>>((const unsigned short*)x, flag);

    // one conversion dispatch: x | weights | mask+vectors
    conv_all_k<<<6153, 256, 0, stream>>>(x, Wq, Wk, Wv, Wo, mask,
                                         bq, bk, bv, bo, lnw, lnb,
                                         xb, wqb, maskf, bqf, bkf, bvf,
                                         bof, lnwf, lnbf, flag);

    dim3 gqkv(Hc / 128, Mc / 128, 3);
    qkv_gemm<<<gqkv, 256, 0, stream>>>(xb, wqb, bqf, wkb, bkf, wvb, bvf, qb, kb, vtb);
    attention<<<dim3(Bc * NHc * (Sc / 256)), 256, 0, stream>>>(qb, kb, vtb, maskf, cb);
    oproj_gemm<<<dim3(Hc / 128, Mc / 128), 256, 0, stream>>>(cb, wob, bof, xb, hb);
    layernorm_k<<<dim3(Mc), 256, 0, stream>>>(hb, lnwf, lnbf, d_out, flag);
}

// Round 4
// 342.044 us; speedup vs baseline: 1.0016x; 1.0016x over previous
//
#include <hip/hip_runtime.h>

typedef __bf16 bf16;
typedef __bf16 bf16x8 __attribute__((ext_vector_type(8)));
typedef __bf16 bf16x4 __attribute__((ext_vector_type(4)));
typedef float floatx4 __attribute__((ext_vector_type(4)));
typedef int   intx4  __attribute__((ext_vector_type(4)));
typedef int   intx2  __attribute__((ext_vector_type(2)));

#define MFMA16(a,b,c) __builtin_amdgcn_mfma_f32_16x16x32_bf16((a),(b),(c),0,0,0)

constexpr int Bc  = 4;
constexpr int Sc  = 2048;
constexpr int Hc  = 1024;
constexpr int NHc = 16;
constexpr int HDc = 64;
constexpr int Mc  = Bc * Sc;       // 8192 rows
constexpr int KIT = Hc / 32;       // 32 k-iterations
constexpr float L2E = 1.44269504088896f;

union U64  { bf16x4 h; intx2 i; };

// async global->LDS, 16B per lane (dest must be wave-uniform base + lane*16)
__device__ __forceinline__ void ld16(const bf16* g, bf16* l) {
    __builtin_amdgcn_global_load_lds(
        (const __attribute__((address_space(1))) void*)g,
        (__attribute__((address_space(3))) void*)l, 16, 0, 0);
}

// ---------------------------------------------------------------------------
// dtype detection (flag=1 -> inputs are fp32)
// ---------------------------------------------------------------------------
__global__ void detect_k(const unsigned short* __restrict__ x, int* __restrict__ flag)
{
    if (threadIdx.x == 0 && blockIdx.x == 0) {
        float mx = 0.f;
        for (int i = 0; i < 256; ++i) {
            unsigned int bits = ((unsigned int)x[i]) << 16;
            float v = __uint_as_float(bits);
            if (!isfinite(v)) { mx = 1e30f; break; }
            mx = fmaxf(mx, fabsf(v));
        }
        *flag = (mx > 1e6f) ? 1 : 0;
    }
}

// ---------------------------------------------------------------------------
// One merged conversion kernel: x (1048576 g8) | 4 weights (524288 g8) |
// mask+6 vectors (1792 g8)
// ---------------------------------------------------------------------------
__global__ __launch_bounds__(256)
void conv_all_k(const void* __restrict__ x,
                const void* __restrict__ Wq, const void* __restrict__ Wk,
                const void* __restrict__ Wv, const void* __restrict__ Wo,
                const void* __restrict__ mask,
                const void* __restrict__ bq, const void* __restrict__ bk,
                const void* __restrict__ bv, const void* __restrict__ bo,
                const void* __restrict__ lnw, const void* __restrict__ lnb,
                bf16* __restrict__ xb, bf16* __restrict__ wdst,
                float* maskf, float* bqf, float* bkf, float* bvf,
                float* bof, float* lnwf, float* lnbf,
                const int* __restrict__ flag)
{
    const int g = blockIdx.x * 256 + threadIdx.x;
    const int fl = *flag;
    if (g < 1048576) {
        if (fl) {
            const float* s = (const float*)x + (size_t)g * 8;
            union { intx4 v; bf16 e[8]; } o;
#pragma unroll
            for (int j = 0; j < 8; ++j) o.e[j] = (bf16)s[j];
            *(intx4*)(xb + (size_t)g * 8) = o.v;
        } else {
            *(intx4*)(xb + (size_t)g * 8) = *((const intx4*)x + g);
        }
    } else if (g < 1048576 + 524288) {
        const int gw = g - 1048576;
        const int wsel = gw >> 17, go = gw & 131071;
        const void* s = (wsel == 0) ? Wq : (wsel == 1) ? Wk : (wsel == 2) ? Wv : Wo;
        if (fl) {
            const float* sp = (const float*)s + (size_t)go * 8;
            union { intx4 v; bf16 e[8]; } o;
#pragma unroll
            for (int j = 0; j < 8; ++j) o.e[j] = (bf16)sp[j];
            *(intx4*)(wdst + (size_t)gw * 8) = o.v;
        } else {
            *(intx4*)(wdst + (size_t)gw * 8) = *((const intx4*)s + go);
        }
    } else {
        const int gs = g - 1048576 - 524288;
        if (gs >= 1792) return;
        const void* src; float* dst; int off; float scl = 1.0f;
        if (gs < 1024) { src = mask; dst = maskf; off = gs * 8; scl = L2E; }
        else {
            const int a = (gs - 1024) >> 7;
            off = ((gs - 1024) & 127) * 8;
            switch (a) {
                case 0: src = bq;  dst = bqf;  break;
                case 1: src = bk;  dst = bkf;  break;
                case 2: src = bv;  dst = bvf;  break;
                case 3: src = bo;  dst = bof;  break;
                case 4: src = lnw; dst = lnwf; break;
                default: src = lnb; dst = lnbf; break;
            }
        }
        if (fl) {
            const float* s = (const float*)src + off;
#pragma unroll
            for (int j = 0; j < 8; ++j) dst[off + j] = s[j] * scl;
        } else {
            union { intx4 v; bf16 e[8]; } u;
            u.v = *(const intx4*)((const bf16*)src + off);
#pragma unroll
            for (int j = 0; j < 8; ++j) dst[off + j] = (float)u.e[j] * scl;
        }
    }
}

// ---------------------------------------------------------------------------
// GEMM core: 128x128 tile over K=1024, A/W row-major.
// 2-phase pipelined (T3 minimum): double-buffered LDS, stage(kb+1) issued
// BEFORE ds_read+MFMA of kb, ONE barrier per K-step. As/Bs each hold
// 2 x 4096 elems (two tile buffers).
// SWAP=0: acc[i][j] = C[xrow-block i][feat-block j]
// SWAP=1: acc[i][j] = C[feat-block j][xrow-block i] (lane cols = xrow)
// ---------------------------------------------------------------------------
template<int SWAP>
__device__ __forceinline__
void gemm_core(const bf16* __restrict__ A, const bf16* __restrict__ W,
               int m0, int n0, int t, bf16* As, bf16* Bs, floatx4 (&acc)[4][4])
{
    const int l  = t & 63, w = t >> 6;
    const int wr = w >> 1, wc = w & 1;
    const int lq = l >> 4, ln = l & 15;
    const int srow = t >> 2;            // 0..63
    const int scol = (t & 3) * 8;       // 0,8,16,24

    const bf16* a0 = A + (size_t)(m0 + srow) * Hc + scol;
    const bf16* b0 = W + (size_t)(n0 + srow) * Hc + scol;
    const int dst = srow * 32 + scol;   // lane-linear within a tile buffer

    auto stage = [&](int buf, int kb) {
        const int off = kb * 32;
        bf16* dA = As + buf * 4096;
        bf16* dB = Bs + buf * 4096;
        ld16(a0 + off,           dA + dst);
        ld16(a0 + 64 * Hc + off, dA + 64 * 32 + dst);
        ld16(b0 + off,           dB + dst);
        ld16(b0 + 64 * Hc + off, dB + 64 * 32 + dst);
    };

    stage(0, 0);
    int cur = 0;
    for (int kb = 0; kb < KIT; ++kb) {
        __syncthreads();                 // buf[cur] ready; buf[cur^1] readers done
        if (kb + 1 < KIT) stage(cur ^ 1, kb + 1);

        const bf16* Ab = As + cur * 4096;
        const bf16* Bb = Bs + cur * 4096;
        bf16x8 af[4], bw[4];
#pragma unroll
        for (int i = 0; i < 4; ++i)
            af[i] = *(const bf16x8*)&Ab[(wr * 64 + i * 16 + ln) * 32 + lq * 8];
#pragma unroll
        for (int j = 0; j < 4; ++j)
            bw[j] = *(const bf16x8*)&Bb[(wc * 64 + j * 16 + ln) * 32 + lq * 8];

        __builtin_amdgcn_s_setprio(1);
#pragma unroll
        for (int i = 0; i < 4; ++i)
#pragma unroll
            for (int j = 0; j < 4; ++j)
                acc[i][j] = SWAP ? MFMA16(bw[j], af[i], acc[i][j])
                                 : MFMA16(af[i], bw[j], acc[i][j]);
        __builtin_amdgcn_s_setprio(0);
        cur ^= 1;
    }
}

// chunked XCD remap for a (8 x 64) tile grid: each XCD owns 8 contiguous
// row-panels -> A-panel L2-resident per XCD, W fully L2-resident. Bijective.
__device__ __forceinline__ void xcd_remap(int bx, int by, int& m0, int& n0)
{
    const int flat = by * 8 + bx;            // dispatch-linear id, 0..511
    const int sw   = (flat & 7) * 64 + (flat >> 3);
    m0 = (sw >> 3) * 128;
    n0 = (sw & 7) * 128;
}

// ---------------------------------------------------------------------------
// Fused QKV: z=0 -> q (scaled by 0.125*log2e) [B,NH,S,HD]; z=1 -> k;
// z=2 -> V^T [B,NH,HD,S] via LDS transpose
// ---------------------------------------------------------------------------
__global__ __launch_bounds__(256)
void qkv_gemm(const bf16* __restrict__ x,
              const bf16* __restrict__ Wq, const float* __restrict__ bq,
              const bf16* __restrict__ Wk, const float* __restrict__ bk,
              const bf16* __restrict__ Wv, const float* __restrict__ bv,
              bf16* __restrict__ qo, bf16* __restrict__ ko, bf16* __restrict__ vto)
{
    __shared__ __align__(16) bf16 smem[16384];  // 2 x (2x4096) dbuf; Ct reuse
    const int z = blockIdx.z;
    const bf16*  W    = (z == 0) ? Wq : (z == 1) ? Wk : Wv;
    const float* bias = (z == 0) ? bq : (z == 1) ? bk : bv;

    int m0, n0;
    xcd_remap(blockIdx.x, blockIdx.y, m0, n0);
    const int t  = threadIdx.x;
    const int l  = t & 63, w = t >> 6;
    const int wr = w >> 1, wc = w & 1;
    const int lq = l >> 4, ln = l & 15;

    if (z < 2) {
        floatx4 acc[4][4] = {};
        gemm_core<1>(x, W, m0, n0, t, smem, smem + 8192, acc);
        bf16* out = (z == 0) ? qo : ko;
        const float sc = (z == 0) ? 0.125f * L2E : 1.0f;
#pragma unroll
        for (int j = 0; j < 4; ++j) {
            const int feat = n0 + wc * 64 + j * 16 + lq * 4;   // 4 consecutive
            const floatx4 bb = *(const floatx4*)&bias[feat];
            const int hh = feat >> 6, dd = feat & 63;
#pragma unroll
            for (int i = 0; i < 4; ++i) {
                const int xrow = m0 + wr * 64 + i * 16 + ln;
                const int bi = xrow >> 11, si = xrow & (Sc - 1);
                U64 pk;
#pragma unroll
                for (int r = 0; r < 4; ++r) pk.h[r] = (bf16)((acc[i][j][r] + bb[r]) * sc);
                *(intx2*)&out[(((size_t)bi * NHc + hh) * Sc + si) * HDc + dd] = pk.i;
            }
        }
    } else {
        floatx4 acc[4][4] = {};
        gemm_core<0>(x, W, m0, n0, t, smem, smem + 8192, acc);
        // transpose epilogue: Ct[64 cols][136 rows], two col-halves
        bf16* Ct = smem;
        const int bi = m0 >> 11, s0 = m0 & (Sc - 1);
        for (int h2 = 0; h2 < 2; ++h2) {
            __syncthreads();
            if (wc == h2) {
#pragma unroll
                for (int j = 0; j < 4; ++j) {
                    const int c = j * 16 + ln;
                    const float bb = bias[n0 + h2 * 64 + c];
#pragma unroll
                    for (int i = 0; i < 4; ++i) {
                        U64 pk;
#pragma unroll
                        for (int r = 0; r < 4; ++r) pk.h[r] = (bf16)(acc[i][j][r] + bb);
                        *(intx2*)&Ct[c * 136 + wr * 64 + i * 16 + lq * 4] = pk.i;
                    }
                }
            }
            __syncthreads();
#pragma unroll
            for (int u = 0; u < 4; ++u) {
                const int id = t + 256 * u;           // 0..1023
                const int c = id >> 4, rg = id & 15;
                const int hh = (n0 >> 6) + h2;
                intx4 val = *(const intx4*)&Ct[c * 136 + rg * 8];
                *(intx4*)&vto[(((size_t)bi * NHc + hh) * HDc + c) * Sc + s0 + rg * 8] = val;
            }
        }
    }
}

// ---------------------------------------------------------------------------
// Output projection + bias + residual -> h (bf16), b64 loads/stores
// ---------------------------------------------------------------------------
__global__ __launch_bounds__(256)
void oproj_gemm(const bf16* __restrict__ ctx, const bf16* __restrict__ Wo,
                const float* __restrict__ bo, const bf16* __restrict__ xb,
                bf16* __restrict__ hout)
{
    __shared__ __align__(16) bf16 smem[16384];
    int m0, n0;
    xcd_remap(blockIdx.x, blockIdx.y, m0, n0);
    const int t  = threadIdx.x;
    floatx4 acc[4][4] = {};
    gemm_core<1>(ctx, Wo, m0, n0, t, smem, smem + 8192, acc);

    const int l  = t & 63, w = t >> 6;
    const int wr = w >> 1, wc = w & 1;
    const int lq = l >> 4, ln = l & 15;
#pragma unroll
    for (int j = 0; j < 4; ++j) {
        const int col = n0 + wc * 64 + j * 16 + lq * 4;   // 4 consecutive
        const floatx4 bb = *(const floatx4*)&bo[col];
#pragma unroll
        for (int i = 0; i < 4; ++i) {
            const int row = m0 + wr * 64 + i * 16 + ln;
            U64 rx;
            rx.i = *(const intx2*)&xb[(size_t)row * Hc + col];
            U64 pk;
#pragma unroll
            for (int r = 0; r < 4; ++r)
                pk.h[r] = (bf16)(acc[i][j][r] + bb[r] + (float)rx.h[r]);
            *(intx2*)&hout[(size_t)row * Hc + col] = pk.i;
        }
    }
}

// ---------------------------------------------------------------------------
// Flash attention, S^T formulation, fixed-max softmax.
// 1 WG = 4 waves x 32 q-rows = 128 q-rows; grid 1024 -> 4 blocks/CU
// (16 waves/CU, 4 waves/SIMD) to hide the per-wave serial chain.
// K/V staged via global_load_lds DMA, double-buffered, XOR-swizzled
// (pre-swizzled global source, linear DMA dest), ONE barrier per tile.
// P^T redistribution fully in-register (permlane32/16_swap), no Pt LDS.
// Phases clustered: all QK^T MFMAs | softmax VALU | all PV MFMAs, with
// kf/vf loaded per-kh-half (16 live regs) to stay under 128 VGPRs.
// ---------------------------------------------------------------------------
__global__ __launch_bounds__(256, 4)
void attention(const bf16* __restrict__ q, const bf16* __restrict__ k,
               const bf16* __restrict__ vt, const float* __restrict__ maskf,
               bf16* __restrict__ ctx)
{
    __shared__ __align__(16) bf16 KV[2][2][64][64];   // [dbuf][K|V][row][col] 32 KB

    // XCD-aware remap: raw%8 = XCD; 8 consecutive (b,h) per XCD so each
    // K/V panel is fetched by ONE L2. 1024 % 8 == 0 -> bijective.
    const int raw = blockIdx.x;                 // 0..1023
    const int xcd = raw & 7, jj = raw >> 3;     // jj 0..127
    const int bh  = xcd * 8 + (jj >> 4);
    const int qt  = jj & 15;                    // q-tile of 128 rows
    const int b = bh >> 4, h = bh & 15;
    const int t = threadIdx.x, w = t >> 6, l = t & 63;
    const int lq = l >> 4, ln = l & 15;
    const int q0 = qt * 128 + w * 32;

    const bf16* kg = k  + (size_t)bh * Sc * HDc;
    const bf16* vg = vt + (size_t)bh * HDc * Sc;
    const float* mbase = maskf + b * Sc;        // pre-scaled by log2e

    // DMA staging geometry: wave w covers rows [16w,16w+16) of the 64-row
    // tile in two 8-row calls; lane l -> row +(l>>3), column granule (l&7).
    // Swizzle: LDS granule c of row r holds global granule c ^ (r&7).
    const int rr  = l >> 3;
    const int gsw = ((l & 7) ^ rr) << 3;        // global column offset (elems)
    const int r0  = w * 16 + rr, r1 = r0 + 8;
    const int dco = (l & 7) << 3;               // linear LDS column (elems)

    // Q fragments in registers (B-operand); q pre-scaled by 0.125*log2e
    bf16x8 qf[2][2];
#pragma unroll
    for (int qb = 0; qb < 2; ++qb)
#pragma unroll
        for (int kh = 0; kh < 2; ++kh)
            qf[qb][kh] = *(const bf16x8*)(q + ((size_t)bh * Sc + q0 + qb * 16 + ln) * HDc
                                            + kh * 32 + lq * 8);

    floatx4 o[2][4] = {};
    float dacc[2] = {0.f, 0.f};

    auto stage = [&](int buf, int kt) {
        bf16* Kd = &KV[buf][0][0][0];
        bf16* Vd = &KV[buf][1][0][0];
        ld16(kg + (size_t)(kt * 64 + r0) * HDc + gsw, Kd + r0 * 64 + dco);
        ld16(kg + (size_t)(kt * 64 + r1) * HDc + gsw, Kd + r1 * 64 + dco);
        ld16(vg + (size_t)r0 * Sc + kt * 64 + gsw,    Vd + r0 * 64 + dco);
        ld16(vg + (size_t)r1 * Sc + kt * 64 + gsw,    Vd + r1 * 64 + dco);
    };

    stage(0, 0);
    int cur = 0;
    const int sw = ln & 7;

    for (int kt = 0; kt < Sc / 64; ++kt) {
        __syncthreads();                 // drains own vmcnt -> buf[cur] ready
        if (kt + 1 < Sc / 64) stage(cur ^ 1, kt + 1);

        const bf16* Kb = &KV[cur][0][0][0];
        const bf16* Vb = &KV[cur][1][0][0];

        // S^T accumulators init = mask (log2 domain) -- free add
        floatx4 s[2][4];
#pragma unroll
        for (int cb = 0; cb < 4; ++cb) {
            const floatx4 mv = *(const floatx4*)(mbase + kt * 64 + cb * 16 + lq * 4);
            s[0][cb] = mv;
            s[1][cb] = mv;
        }

        // QK^T phase: per kh-half load kf (16 regs) then 8 MFMAs
#pragma unroll
        for (int kh = 0; kh < 2; ++kh) {
            bf16x8 kf[4];
#pragma unroll
            for (int cb = 0; cb < 4; ++cb) {
                const int cc = ((kh * 4 + lq) ^ sw) << 3;
                kf[cb] = *(const bf16x8*)&Kb[(cb * 16 + ln) * 64 + cc];
            }
            __builtin_amdgcn_s_setprio(1);
#pragma unroll
            for (int qb = 0; qb < 2; ++qb)
#pragma unroll
                for (int cb = 0; cb < 4; ++cb)
                    s[qb][cb] = MFMA16(kf[cb], qf[qb][kh], s[qb][cb]);
            __builtin_amdgcn_s_setprio(0);
        }

        // softmax VALU phase: p = exp2(s), pack, in-register P^T transpose
        bf16x8 pf[2][2];
#pragma unroll
        for (int qb = 0; qb < 2; ++qb) {
            unsigned int D[4][2];
            float ds = 0.f;
#pragma unroll
            for (int cb = 0; cb < 4; ++cb)
#pragma unroll
                for (int i = 0; i < 2; ++i) {
                    const float e0 = __builtin_amdgcn_exp2f(s[qb][cb][2 * i]);
                    const float e1 = __builtin_amdgcn_exp2f(s[qb][cb][2 * i + 1]);
                    ds += e0 + e1;
                    union { unsigned int u; bf16 e[2]; } pk2;
                    pk2.e[0] = (bf16)e0; pk2.e[1] = (bf16)e1;
                    D[cb][i] = pk2.u;
                }
            dacc[qb] += ds;

            // 4-lane transpose over lanes {l, l+16, l+32, l+48}
            unsigned int F0[4], F1[4];
            {
                unsigned int A, B;
                A = D[0][0]; B = D[1][0];
                asm("v_permlane32_swap_b32 %0, %1" : "+v"(A), "+v"(B));
                asm("v_permlane16_swap_b32 %0, %1" : "+v"(A), "+v"(B));
                F0[0] = A; F0[2] = B;
                A = D[0][1]; B = D[1][1];
                asm("v_permlane32_swap_b32 %0, %1" : "+v"(A), "+v"(B));
                asm("v_permlane16_swap_b32 %0, %1" : "+v"(A), "+v"(B));
                F0[1] = A; F0[3] = B;
                A = D[2][0]; B = D[3][0];
                asm("v_permlane32_swap_b32 %0, %1" : "+v"(A), "+v"(B));
                asm("v_permlane16_swap_b32 %0, %1" : "+v"(A), "+v"(B));
                F1[0] = A; F1[2] = B;
                A = D[2][1]; B = D[3][1];
                asm("v_permlane32_swap_b32 %0, %1" : "+v"(A), "+v"(B));
                asm("v_permlane16_swap_b32 %0, %1" : "+v"(A), "+v"(B));
                F1[1] = A; F1[3] = B;
            }
            union { unsigned int u[4]; bf16x8 v; } P0, P1;
#pragma unroll
            for (int d = 0; d < 4; ++d) { P0.u[d] = F0[d]; P1.u[d] = F1[d]; }
            pf[qb][0] = P0.v;
            pf[qb][1] = P1.v;
        }

        // PV phase: per kh-half load vf (16 regs) then 8 MFMAs
#pragma unroll
        for (int kh = 0; kh < 2; ++kh) {
            bf16x8 vf[4];
#pragma unroll
            for (int db = 0; db < 4; ++db) {
                const int cc = ((kh * 4 + lq) ^ sw) << 3;
                vf[db] = *(const bf16x8*)&Vb[(db * 16 + ln) * 64 + cc];
            }
            __builtin_amdgcn_s_setprio(1);
#pragma unroll
            for (int qb = 0; qb < 2; ++qb)
#pragma unroll
                for (int db = 0; db < 4; ++db)
                    o[qb][db] = MFMA16(vf[db], pf[qb][kh], o[qb][db]);
            __builtin_amdgcn_s_setprio(0);
        }
        cur ^= 1;
    }

    // finish denominators (sum over the 4-lane stride-16 group), store ctx
#pragma unroll
    for (int qb = 0; qb < 2; ++qb) {
        float dsum = dacc[qb];
        dsum += __shfl_xor(dsum, 16, 64);
        dsum += __shfl_xor(dsum, 32, 64);
        const float li = 1.f / dsum;
        const int qg = q0 + qb * 16 + ln;
#pragma unroll
        for (int db = 0; db < 4; ++db) {
            U64 pk;
#pragma unroll
            for (int r = 0; r < 4; ++r) pk.h[r] = (bf16)(o[qb][db][r] * li);
            *(intx2*)&ctx[((size_t)b * Sc + qg) * Hc + h * HDc + db * 16 + lq * 4] = pk.i;
        }
    }
}

// ---------------------------------------------------------------------------
// LayerNorm; output dtype keyed off flag
// ---------------------------------------------------------------------------
__global__ __launch_bounds__(256)
void layernorm_k(const bf16* __restrict__ hbuf, const float* __restrict__ lw,
                 const float* __restrict__ lb, void* __restrict__ outp,
                 const int* __restrict__ flag)
{
    const int row = blockIdx.x;
    const int t = threadIdx.x;
    const bf16* hp = hbuf + (size_t)row * Hc;

    union { intx2 i2; bf16 e[4]; } pk;
    pk.i2 = *(const intx2*)(hp + t * 4);
    float v[4], sum = 0.f, sq = 0.f;
#pragma unroll
    for (int i = 0; i < 4; ++i) {
        v[i] = (float)pk.e[i];
        sum += v[i];
        sq  += v[i] * v[i];
    }
#pragma unroll
    for (int off = 1; off < 64; off <<= 1) {
        sum += __shfl_xor(sum, off, 64);
        sq  += __shfl_xor(sq,  off, 64);
    }
    __shared__ float ssum[4], ssq[4];
    const int w = t >> 6;
    if ((t & 63) == 0) { ssum[w] = sum; ssq[w] = sq; }
    __syncthreads();
    sum = ssum[0] + ssum[1] + ssum[2] + ssum[3];
    sq  = ssq[0]  + ssq[1]  + ssq[2]  + ssq[3];

    const float mean = sum * (1.f / (float)Hc);
    const float var  = sq * (1.f / (float)Hc) - mean * mean;
    const float rstd = rsqrtf(var + 1e-12f);

    float ov[4];
#pragma unroll
    for (int i = 0; i < 4; ++i) {
        const int c = t * 4 + i;
        ov[i] = lw[c] * (v[i] - mean) * rstd + lb[c];
    }
    if (*flag) {
        float* of = (float*)outp + (size_t)row * Hc + t * 4;
#pragma unroll
        for (int i = 0; i < 4; ++i) of[i] = ov[i];
    } else {
        union { intx2 i2; bf16 e[4]; } po;
#pragma unroll
        for (int i = 0; i < 4; ++i) po.e[i] = (bf16)ov[i];
        *(intx2*)((bf16*)outp + (size_t)row * Hc + t * 4) = po.i2;
    }
}

// ---------------------------------------------------------------------------
extern "C" void kernel_launch(void* const* d_in, const int* in_sizes, int n_in,
                              void* d_out, int out_size, void* d_ws, size_t ws_size,
                              hipStream_t stream)
{
    const void* x    = d_in[0];
    const void* mask = d_in[1];
    const void* Wq   = d_in[2];
    const void* bq   = d_in[3];
    const void* Wk   = d_in[4];
    const void* bk   = d_in[5];
    const void* Wv   = d_in[6];
    const void* bv   = d_in[7];
    const void* Wo   = d_in[8];
    const void* bo   = d_in[9];
    const void* lnw  = d_in[10];
    const void* lnb  = d_in[11];

    char* ws = (char*)d_ws;
    const size_t MB = 1024 * 1024;
    int*   flag  = (int*)ws;
    float* maskf = (float*)(ws + 4096);
    float* bqf   = (float*)(ws + 64 * 1024);
    float* bkf   = bqf + Hc;
    float* bvf   = bkf + Hc;
    float* bof   = bvf + Hc;
    float* lnwf  = bof + Hc;
    float* lnbf  = lnwf + Hc;
    bf16* xb  = (bf16*)(ws + 1 * MB);    // 16 MB
    bf16* wqb = (bf16*)(ws + 17 * MB);   // 2 MB each, contiguous wq|wk|wv|wo
    bf16* wkb = (bf16*)(ws + 19 * MB);
    bf16* wvb = (bf16*)(ws + 21 * MB);
    bf16* wob = (bf16*)(ws + 23 * MB);
    bf16* qb  = (bf16*)(ws + 25 * MB);   // 16 MB
    bf16* kb  = (bf16*)(ws + 41 * MB);
    bf16* vtb = (bf16*)(ws + 57 * MB);   // V^T
    bf16* cb  = (bf16*)(ws + 73 * MB);   // ctx; high water 89 MB
    bf16* hb  = qb;                      // h reuses q (dead after attention)

    detect_k<<<1, 64, 0, stream>>>((const unsigned short*)x, flag);

    // one conversion dispatch: x | weights | mask+vectors
    conv_all_k<<<6153, 256, 0, stream>>>(x, Wq, Wk, Wv, Wo, mask,
                                         bq, bk, bv, bo, lnw, lnb,
                                         xb, wqb, maskf, bqf, bkf, bvf,
                                         bof, lnwf, lnbf, flag);

    dim3 gqkv(Hc / 128, Mc / 128, 3);
    qkv_gemm<<<gqkv, 256, 0, stream>>>(xb, wqb, bqf, wkb, bkf, wvb, bvf, qb, kb, vtb);
    attention<<<dim3(Bc * NHc * (Sc / 128)), 256, 0, stream>>>(qb, kb, vtb, maskf, cb);
    oproj_gemm<<<dim3(Hc / 128, Mc / 128), 256, 0, stream>>>(cb, wob, bof, xb, hb);
    layernorm_k<<<dim3(Mc), 256, 0, stream>>>(hb, lnwf, lnbf, d_out, flag);
}

// Round 5
// 340.893 us; speedup vs baseline: 1.0050x; 1.0034x over previous
//
#include <hip/hip_runtime.h>

typedef __bf16 bf16;
typedef __bf16 bf16x8 __attribute__((ext_vector_type(8)));
typedef __bf16 bf16x4 __attribute__((ext_vector_type(4)));
typedef float floatx4 __attribute__((ext_vector_type(4)));
typedef int   intx4  __attribute__((ext_vector_type(4)));
typedef int   intx2  __attribute__((ext_vector_type(2)));

#define MFMA16(a,b,c) __builtin_amdgcn_mfma_f32_16x16x32_bf16((a),(b),(c),0,0,0)

constexpr int Bc  = 4;
constexpr int Sc  = 2048;
constexpr int Hc  = 1024;
constexpr int NHc = 16;
constexpr int HDc = 64;
constexpr int Mc  = Bc * Sc;       // 8192 rows
constexpr int KIT = Hc / 32;       // 32 k-iterations
constexpr float L2E = 1.44269504088896f;

union U64  { bf16x4 h; intx2 i; };

// async global->LDS, 16B per lane (dest must be wave-uniform base + lane*16)
__device__ __forceinline__ void ld16(const bf16* g, bf16* l) {
    __builtin_amdgcn_global_load_lds(
        (const __attribute__((address_space(1))) void*)g,
        (__attribute__((address_space(3))) void*)l, 16, 0, 0);
}

// ---------------------------------------------------------------------------
// dtype detection (flag=1 -> inputs are fp32)
// ---------------------------------------------------------------------------
__global__ void detect_k(const unsigned short* __restrict__ x, int* __restrict__ flag)
{
    if (threadIdx.x == 0 && blockIdx.x == 0) {
        float mx = 0.f;
        for (int i = 0; i < 256; ++i) {
            unsigned int bits = ((unsigned int)x[i]) << 16;
            float v = __uint_as_float(bits);
            if (!isfinite(v)) { mx = 1e30f; break; }
            mx = fmaxf(mx, fabsf(v));
        }
        *flag = (mx > 1e6f) ? 1 : 0;
    }
}

// ---------------------------------------------------------------------------
// One merged conversion kernel: x (1048576 g8) | 4 weights (524288 g8) |
// mask+6 vectors (1792 g8)
// ---------------------------------------------------------------------------
__global__ __launch_bounds__(256)
void conv_all_k(const void* __restrict__ x,
                const void* __restrict__ Wq, const void* __restrict__ Wk,
                const void* __restrict__ Wv, const void* __restrict__ Wo,
                const void* __restrict__ mask,
                const void* __restrict__ bq, const void* __restrict__ bk,
                const void* __restrict__ bv, const void* __restrict__ bo,
                const void* __restrict__ lnw, const void* __restrict__ lnb,
                bf16* __restrict__ xb, bf16* __restrict__ wdst,
                float* maskf, float* bqf, float* bkf, float* bvf,
                float* bof, float* lnwf, float* lnbf,
                const int* __restrict__ flag)
{
    const int g = blockIdx.x * 256 + threadIdx.x;
    const int fl = *flag;
    if (g < 1048576) {
        if (fl) {
            const float* s = (const float*)x + (size_t)g * 8;
            union { intx4 v; bf16 e[8]; } o;
#pragma unroll
            for (int j = 0; j < 8; ++j) o.e[j] = (bf16)s[j];
            *(intx4*)(xb + (size_t)g * 8) = o.v;
        } else {
            *(intx4*)(xb + (size_t)g * 8) = *((const intx4*)x + g);
        }
    } else if (g < 1048576 + 524288) {
        const int gw = g - 1048576;
        const int wsel = gw >> 17, go = gw & 131071;
        const void* s = (wsel == 0) ? Wq : (wsel == 1) ? Wk : (wsel == 2) ? Wv : Wo;
        if (fl) {
            const float* sp = (const float*)s + (size_t)go * 8;
            union { intx4 v; bf16 e[8]; } o;
#pragma unroll
            for (int j = 0; j < 8; ++j) o.e[j] = (bf16)sp[j];
            *(intx4*)(wdst + (size_t)gw * 8) = o.v;
        } else {
            *(intx4*)(wdst + (size_t)gw * 8) = *((const intx4*)s + go);
        }
    } else {
        const int gs = g - 1048576 - 524288;
        if (gs >= 1792) return;
        const void* src; float* dst; int off; float scl = 1.0f;
        if (gs < 1024) { src = mask; dst = maskf; off = gs * 8; scl = L2E; }
        else {
            const int a = (gs - 1024) >> 7;
            off = ((gs - 1024) & 127) * 8;
            switch (a) {
                case 0: src = bq;  dst = bqf;  break;
                case 1: src = bk;  dst = bkf;  break;
                case 2: src = bv;  dst = bvf;  break;
                case 3: src = bo;  dst = bof;  break;
                case 4: src = lnw; dst = lnwf; break;
                default: src = lnb; dst = lnbf; break;
            }
        }
        if (fl) {
            const float* s = (const float*)src + off;
#pragma unroll
            for (int j = 0; j < 8; ++j) dst[off + j] = s[j] * scl;
        } else {
            union { intx4 v; bf16 e[8]; } u;
            u.v = *(const intx4*)((const bf16*)src + off);
#pragma unroll
            for (int j = 0; j < 8; ++j) dst[off + j] = (float)u.e[j] * scl;
        }
    }
}

// ---------------------------------------------------------------------------
// GEMM core: 128x128 tile over K=1024, A/W row-major.
// 2-phase pipelined: double-buffered LDS, stage(kb+1) issued BEFORE
// ds_read+MFMA of kb, ONE barrier per K-step.
// SWAP=0: acc[i][j] = C[xrow-block i][feat-block j]
// SWAP=1: acc[i][j] = C[feat-block j][xrow-block i] (lane cols = xrow)
// ---------------------------------------------------------------------------
template<int SWAP>
__device__ __forceinline__
void gemm_core(const bf16* __restrict__ A, const bf16* __restrict__ W,
               int m0, int n0, int t, bf16* As, bf16* Bs, floatx4 (&acc)[4][4])
{
    const int l  = t & 63, w = t >> 6;
    const int wr = w >> 1, wc = w & 1;
    const int lq = l >> 4, ln = l & 15;
    const int srow = t >> 2;            // 0..63
    const int scol = (t & 3) * 8;       // 0,8,16,24

    const bf16* a0 = A + (size_t)(m0 + srow) * Hc + scol;
    const bf16* b0 = W + (size_t)(n0 + srow) * Hc + scol;
    const int dst = srow * 32 + scol;   // lane-linear within a tile buffer

    auto stage = [&](int buf, int kb) {
        const int off = kb * 32;
        bf16* dA = As + buf * 4096;
        bf16* dB = Bs + buf * 4096;
        ld16(a0 + off,           dA + dst);
        ld16(a0 + 64 * Hc + off, dA + 64 * 32 + dst);
        ld16(b0 + off,           dB + dst);
        ld16(b0 + 64 * Hc + off, dB + 64 * 32 + dst);
    };

    stage(0, 0);
    int cur = 0;
    for (int kb = 0; kb < KIT; ++kb) {
        __syncthreads();                 // buf[cur] ready; buf[cur^1] readers done
        if (kb + 1 < KIT) stage(cur ^ 1, kb + 1);

        const bf16* Ab = As + cur * 4096;
        const bf16* Bb = Bs + cur * 4096;
        bf16x8 af[4], bw[4];
#pragma unroll
        for (int i = 0; i < 4; ++i)
            af[i] = *(const bf16x8*)&Ab[(wr * 64 + i * 16 + ln) * 32 + lq * 8];
#pragma unroll
        for (int j = 0; j < 4; ++j)
            bw[j] = *(const bf16x8*)&Bb[(wc * 64 + j * 16 + ln) * 32 + lq * 8];

        __builtin_amdgcn_s_setprio(1);
#pragma unroll
        for (int i = 0; i < 4; ++i)
#pragma unroll
            for (int j = 0; j < 4; ++j)
                acc[i][j] = SWAP ? MFMA16(bw[j], af[i], acc[i][j])
                                 : MFMA16(af[i], bw[j], acc[i][j]);
        __builtin_amdgcn_s_setprio(0);
        cur ^= 1;
    }
}

// chunked XCD remap for a (8 x 64) tile grid: each XCD owns 8 contiguous
// row-panels -> A-panel L2-resident per XCD, W fully L2-resident. Bijective.
__device__ __forceinline__ void xcd_remap(int bx, int by, int& m0, int& n0)
{
    const int flat = by * 8 + bx;            // dispatch-linear id, 0..511
    const int sw   = (flat & 7) * 64 + (flat >> 3);
    m0 = (sw >> 3) * 128;
    n0 = (sw & 7) * 128;
}

// ---------------------------------------------------------------------------
// Fused QKV: z=0 -> q (scaled by 0.125*log2e) [B,NH,S,HD]; z=1 -> k;
// z=2 -> V^T [B,NH,HD,S] via LDS transpose
// ---------------------------------------------------------------------------
__global__ __launch_bounds__(256)
void qkv_gemm(const bf16* __restrict__ x,
              const bf16* __restrict__ Wq, const float* __restrict__ bq,
              const bf16* __restrict__ Wk, const float* __restrict__ bk,
              const bf16* __restrict__ Wv, const float* __restrict__ bv,
              bf16* __restrict__ qo, bf16* __restrict__ ko, bf16* __restrict__ vto)
{
    __shared__ __align__(16) bf16 smem[16384];  // 2 x (2x4096) dbuf; Ct reuse
    const int z = blockIdx.z;
    const bf16*  W    = (z == 0) ? Wq : (z == 1) ? Wk : Wv;
    const float* bias = (z == 0) ? bq : (z == 1) ? bk : bv;

    int m0, n0;
    xcd_remap(blockIdx.x, blockIdx.y, m0, n0);
    const int t  = threadIdx.x;
    const int l  = t & 63, w = t >> 6;
    const int wr = w >> 1, wc = w & 1;
    const int lq = l >> 4, ln = l & 15;

    if (z < 2) {
        floatx4 acc[4][4] = {};
        gemm_core<1>(x, W, m0, n0, t, smem, smem + 8192, acc);
        bf16* out = (z == 0) ? qo : ko;
        const float sc = (z == 0) ? 0.125f * L2E : 1.0f;
#pragma unroll
        for (int j = 0; j < 4; ++j) {
            const int feat = n0 + wc * 64 + j * 16 + lq * 4;   // 4 consecutive
            const floatx4 bb = *(const floatx4*)&bias[feat];
            const int hh = feat >> 6, dd = feat & 63;
#pragma unroll
            for (int i = 0; i < 4; ++i) {
                const int xrow = m0 + wr * 64 + i * 16 + ln;
                const int bi = xrow >> 11, si = xrow & (Sc - 1);
                U64 pk;
#pragma unroll
                for (int r = 0; r < 4; ++r) pk.h[r] = (bf16)((acc[i][j][r] + bb[r]) * sc);
                *(intx2*)&out[(((size_t)bi * NHc + hh) * Sc + si) * HDc + dd] = pk.i;
            }
        }
    } else {
        floatx4 acc[4][4] = {};
        gemm_core<0>(x, W, m0, n0, t, smem, smem + 8192, acc);
        // transpose epilogue: Ct[64 cols][136 rows], two col-halves
        bf16* Ct = smem;
        const int bi = m0 >> 11, s0 = m0 & (Sc - 1);
        for (int h2 = 0; h2 < 2; ++h2) {
            __syncthreads();
            if (wc == h2) {
#pragma unroll
                for (int j = 0; j < 4; ++j) {
                    const int c = j * 16 + ln;
                    const float bb = bias[n0 + h2 * 64 + c];
#pragma unroll
                    for (int i = 0; i < 4; ++i) {
                        U64 pk;
#pragma unroll
                        for (int r = 0; r < 4; ++r) pk.h[r] = (bf16)(acc[i][j][r] + bb);
                        *(intx2*)&Ct[c * 136 + wr * 64 + i * 16 + lq * 4] = pk.i;
                    }
                }
            }
            __syncthreads();
#pragma unroll
            for (int u = 0; u < 4; ++u) {
                const int id = t + 256 * u;           // 0..1023
                const int c = id >> 4, rg = id & 15;
                const int hh = (n0 >> 6) + h2;
                intx4 val = *(const intx4*)&Ct[c * 136 + rg * 8];
                *(intx4*)&vto[(((size_t)bi * NHc + hh) * HDc + c) * Sc + s0 + rg * 8] = val;
            }
        }
    }
}

// ---------------------------------------------------------------------------
// Output projection + bias + residual -> h (bf16), b64 loads/stores
// ---------------------------------------------------------------------------
__global__ __launch_bounds__(256)
void oproj_gemm(const bf16* __restrict__ ctx, const bf16* __restrict__ Wo,
                const float* __restrict__ bo, const bf16* __restrict__ xb,
                bf16* __restrict__ hout)
{
    __shared__ __align__(16) bf16 smem[16384];
    int m0, n0;
    xcd_remap(blockIdx.x, blockIdx.y, m0, n0);
    const int t  = threadIdx.x;
    floatx4 acc[4][4] = {};
    gemm_core<1>(ctx, Wo, m0, n0, t, smem, smem + 8192, acc);

    const int l  = t & 63, w = t >> 6;
    const int wr = w >> 1, wc = w & 1;
    const int lq = l >> 4, ln = l & 15;
#pragma unroll
    for (int j = 0; j < 4; ++j) {
        const int col = n0 + wc * 64 + j * 16 + lq * 4;   // 4 consecutive
        const floatx4 bb = *(const floatx4*)&bo[col];
#pragma unroll
        for (int i = 0; i < 4; ++i) {
            const int row = m0 + wr * 64 + i * 16 + ln;
            U64 rx;
            rx.i = *(const intx2*)&xb[(size_t)row * Hc + col];
            U64 pk;
#pragma unroll
            for (int r = 0; r < 4; ++r)
                pk.h[r] = (bf16)(acc[i][j][r] + bb[r] + (float)rx.h[r]);
            *(intx2*)&hout[(size_t)row * Hc + col] = pk.i;
        }
    }
}

// ---------------------------------------------------------------------------
// Flash attention, S^T formulation, fixed-max softmax.
// 1 WG = 4 waves x 64 q-rows = 256 q-rows (qb=4, the proven-fastest shape).
// T15 one-tile software pipeline: per iteration QK^T(t) then PV(t-1) then
// softmax(t) -- PV no longer depends on this iteration's softmax, so the
// MFMA clusters are independent of the VALU cluster and the Pt write->read
// roundtrip spans a full iteration (latency hidden).
//   K: global_load_lds DMA double-buffer, XOR-swizzled reads (R4-proven,
//      conflict-free), ONE barrier per tile.
//   V: registers only (T14) -- loaded from global one tile ahead, drained
//      by the barrier's vmcnt(0). No V LDS traffic at all.
//   P: wave-private Pt rows in LDS (R0-proven transpose path).
// LDS: 16 KB K-dbuf + 36 KB Pt = 52 KB -> 2 blocks/CU.
// ---------------------------------------------------------------------------
__global__ __launch_bounds__(256, 2)
void attention(const bf16* __restrict__ q, const bf16* __restrict__ k,
               const bf16* __restrict__ vt, const float* __restrict__ maskf,
               bf16* __restrict__ ctx)
{
    __shared__ __align__(16) bf16 Ks[2][64][64];   // K dbuf, swizzled (16 KB)
    __shared__ __align__(16) bf16 Pt[256][72];     // P^T, wave-private rows (36 KB)

    // XCD-aware remap: raw%8 = XCD; 8 consecutive (b,h) per XCD. 512%8==0.
    const int raw = blockIdx.x;                 // 0..511
    const int xcd = raw & 7, jj = raw >> 3;     // jj 0..63
    const int bh  = xcd * 8 + (jj >> 3);
    const int qt  = jj & 7;                     // q-tile of 256 rows
    const int b = bh >> 4, h = bh & 15;
    const int t = threadIdx.x, w = t >> 6, l = t & 63;
    const int lq = l >> 4, ln = l & 15;
    const int q0 = qt * 256 + w * 64;

    const bf16* kg = k  + (size_t)bh * Sc * HDc;
    const bf16* vg = vt + (size_t)bh * HDc * Sc;
    const float* mbase = maskf + b * Sc;        // pre-scaled by log2e

    // K DMA staging geometry (R4-proven): wave w covers rows [16w,16w+16)
    // in two 8-row calls; LDS granule c of row r holds global granule c^(r&7).
    const int rr  = l >> 3;
    const int gsw = ((l & 7) ^ rr) << 3;        // pre-swizzled global col (elems)
    const int r0  = w * 16 + rr, r1 = r0 + 8;
    const int dco = (l & 7) << 3;               // linear LDS col (elems)
    const int sw  = ln & 7;                     // read-side swizzle key

    // Q fragments in registers (B-operand); q pre-scaled by 0.125*log2e
    bf16x8 qf[4][2];
#pragma unroll
    for (int qb = 0; qb < 4; ++qb)
#pragma unroll
        for (int kh = 0; kh < 2; ++kh)
            qf[qb][kh] = *(const bf16x8*)(q + ((size_t)bh * Sc + q0 + qb * 16 + ln) * HDc
                                            + kh * 32 + lq * 8);

    floatx4 o[4][4] = {};
    float dacc[4] = {0.f, 0.f, 0.f, 0.f};
    floatx4 s[4][4];
    bf16x8 vf[4][2];                            // V^T fragments, tile t-1

    auto stageK = [&](int buf, int kt) {
        bf16* Kd = &Ks[buf][0][0];
        ld16(kg + (size_t)(kt * 64 + r0) * HDc + gsw, Kd + r0 * 64 + dco);
        ld16(kg + (size_t)(kt * 64 + r1) * HDc + gsw, Kd + r1 * 64 + dco);
    };
    auto loadV = [&](int kt) {                  // global -> regs, one tile ahead
#pragma unroll
        for (int db = 0; db < 4; ++db)
#pragma unroll
            for (int kh = 0; kh < 2; ++kh)
                vf[db][kh] = *(const bf16x8*)(vg + (size_t)(db * 16 + ln) * Sc
                                                + kt * 64 + kh * 32 + lq * 8);
    };
    auto doQKT = [&](int kt, int cur) {
        floatx4 mvl[4];
#pragma unroll
        for (int cb = 0; cb < 4; ++cb)
            mvl[cb] = *(const floatx4*)(mbase + kt * 64 + cb * 16 + lq * 4);
        bf16x8 kf[4][2];
#pragma unroll
        for (int cb = 0; cb < 4; ++cb)
#pragma unroll
            for (int kh = 0; kh < 2; ++kh)
                kf[cb][kh] = *(const bf16x8*)&Ks[cur][cb * 16 + ln]
                                               [((kh * 4 + lq) ^ sw) << 3];
#pragma unroll
        for (int qb = 0; qb < 4; ++qb)
#pragma unroll
            for (int cb = 0; cb < 4; ++cb)
                s[qb][cb] = mvl[cb];
        __builtin_amdgcn_s_setprio(1);
#pragma unroll
        for (int kh = 0; kh < 2; ++kh)
#pragma unroll
            for (int qb = 0; qb < 4; ++qb)
#pragma unroll
                for (int cb = 0; cb < 4; ++cb)
                    s[qb][cb] = MFMA16(kf[cb][kh], qf[qb][kh], s[qb][cb]);
        __builtin_amdgcn_s_setprio(0);
    };
    auto doPV = [&]() {                         // consumes Pt(t-1) + vf(t-1)
        __builtin_amdgcn_s_setprio(1);
#pragma unroll
        for (int qb = 0; qb < 4; ++qb) {
            const bf16x8 pf0 = *(const bf16x8*)&Pt[w * 64 + qb * 16 + ln][lq * 8];
            const bf16x8 pf1 = *(const bf16x8*)&Pt[w * 64 + qb * 16 + ln][32 + lq * 8];
#pragma unroll
            for (int db = 0; db < 4; ++db) {
                o[qb][db] = MFMA16(vf[db][0], pf0, o[qb][db]);
                o[qb][db] = MFMA16(vf[db][1], pf1, o[qb][db]);
            }
        }
        __builtin_amdgcn_s_setprio(0);
    };
    auto doSoftmax = [&]() {                    // s -> exp2 -> Pt, denom in f32
#pragma unroll
        for (int qb = 0; qb < 4; ++qb) {
            float ds = 0.f;
#pragma unroll
            for (int cb = 0; cb < 4; ++cb) {
                U64 pk;
#pragma unroll
                for (int r = 0; r < 4; ++r) {
                    const float e = __builtin_amdgcn_exp2f(s[qb][cb][r]);
                    ds += e;
                    pk.h[r] = (bf16)e;
                }
                *(intx2*)&Pt[w * 64 + qb * 16 + ln][cb * 16 + lq * 4] = pk.i;
            }
            dacc[qb] += ds;
        }
    };

    // prologue: stage K(0), issue V(0) loads
    stageK(0, 0);
    loadV(0);
    int cur = 0;

    // peeled iteration 0: no PV yet
    __syncthreads();                  // K(0) in LDS, V(0) in regs (vmcnt drained)
    stageK(1, 1);
    doQKT(0, 0);
    doSoftmax();
    cur = 1;

    for (int kt = 1; kt < Sc / 64; ++kt) {
        __syncthreads();              // K(kt) ready; prev-iter LDS reads done
        if (kt + 1 < Sc / 64) stageK(cur ^ 1, kt + 1);
        doQKT(kt, cur);               // MFMA cluster 1 (tile kt)
        doPV();                       // MFMA cluster 2 (tile kt-1), indep. of softmax
        loadV(kt);                    // issue V(kt) global loads (used next iter)
        doSoftmax();                  // VALU cluster (tile kt), overlappable
        cur ^= 1;
    }
    doPV();                           // epilogue: PV(31)

    // finish denominators (sum over the 4-lane stride-16 group), store ctx
#pragma unroll
    for (int qb = 0; qb < 4; ++qb) {
        float dsum = dacc[qb];
        dsum += __shfl_xor(dsum, 16, 64);
        dsum += __shfl_xor(dsum, 32, 64);
        const float li = 1.f / dsum;
        const int qg = q0 + qb * 16 + ln;
#pragma unroll
        for (int db = 0; db < 4; ++db) {
            U64 pk;
#pragma unroll
            for (int r = 0; r < 4; ++r) pk.h[r] = (bf16)(o[qb][db][r] * li);
            *(intx2*)&ctx[((size_t)b * Sc + qg) * Hc + h * HDc + db * 16 + lq * 4] = pk.i;
        }
    }
}

// ---------------------------------------------------------------------------
// LayerNorm; output dtype keyed off flag
// ---------------------------------------------------------------------------
__global__ __launch_bounds__(256)
void layernorm_k(const bf16* __restrict__ hbuf, const float* __restrict__ lw,
                 const float* __restrict__ lb, void* __restrict__ outp,
                 const int* __restrict__ flag)
{
    const int row = blockIdx.x;
    const int t = threadIdx.x;
    const bf16* hp = hbuf + (size_t)row * Hc;

    union { intx2 i2; bf16 e[4]; } pk;
    pk.i2 = *(const intx2*)(hp + t * 4);
    float v[4], sum = 0.f, sq = 0.f;
#pragma unroll
    for (int i = 0; i < 4; ++i) {
        v[i] = (float)pk.e[i];
        sum += v[i];
        sq  += v[i] * v[i];
    }
#pragma unroll
    for (int off = 1; off < 64; off <<= 1) {
        sum += __shfl_xor(sum, off, 64);
        sq  += __shfl_xor(sq,  off, 64);
    }
    __shared__ float ssum[4], ssq[4];
    const int w = t >> 6;
    if ((t & 63) == 0) { ssum[w] = sum; ssq[w] = sq; }
    __syncthreads();
    sum = ssum[0] + ssum[1] + ssum[2] + ssum[3];
    sq  = ssq[0]  + ssq[1]  + ssq[2]  + ssq[3];

    const float mean = sum * (1.f / (float)Hc);
    const float var  = sq * (1.f / (float)Hc) - mean * mean;
    const float rstd = rsqrtf(var + 1e-12f);

    float ov[4];
#pragma unroll
    for (int i = 0; i < 4; ++i) {
        const int c = t * 4 + i;
        ov[i] = lw[c] * (v[i] - mean) * rstd + lb[c];
    }
    if (*flag) {
        float* of = (float*)outp + (size_t)row * Hc + t * 4;
#pragma unroll
        for (int i = 0; i < 4; ++i) of[i] = ov[i];
    } else {
        union { intx2 i2; bf16 e[4]; } po;
#pragma unroll
        for (int i = 0; i < 4; ++i) po.e[i] = (bf16)ov[i];
        *(intx2*)((bf16*)outp + (size_t)row * Hc + t * 4) = po.i2;
    }
}

// ---------------------------------------------------------------------------
extern "C" void kernel_launch(void* const* d_in, const int* in_sizes, int n_in,
                              void* d_out, int out_size, void* d_ws, size_t ws_size,
                              hipStream_t stream)
{
    const void* x    = d_in[0];
    const void* mask = d_in[1];
    const void* Wq   = d_in[2];
    const void* bq   = d_in[3];
    const void* Wk   = d_in[4];
    const void* bk   = d_in[5];
    const void* Wv   = d_in[6];
    const void* bv   = d_in[7];
    const void* Wo   = d_in[8];
    const void* bo   = d_in[9];
    const void* lnw  = d_in[10];
    const void* lnb  = d_in[11];

    char* ws = (char*)d_ws;
    const size_t MB = 1024 * 1024;
    int*   flag  = (int*)ws;
    float* maskf = (float*)(ws + 4096);
    float* bqf   = (float*)(ws + 64 * 1024);
    float* bkf   = bqf + Hc;
    float* bvf   = bkf + Hc;
    float* bof   = bvf + Hc;
    float* lnwf  = bof + Hc;
    float* lnbf  = lnwf + Hc;
    bf16* xb  = (bf16*)(ws + 1 * MB);    // 16 MB
    bf16* wqb = (bf16*)(ws + 17 * MB);   // 2 MB each, contiguous wq|wk|wv|wo
    bf16* wkb = (bf16*)(ws + 19 * MB);
    bf16* wvb = (bf16*)(ws + 21 * MB);
    bf16* wob = (bf16*)(ws + 23 * MB);
    bf16* qb  = (bf16*)(ws + 25 * MB);   // 16 MB
    bf16* kb  = (bf16*)(ws + 41 * MB);
    bf16* vtb = (bf16*)(ws + 57 * MB);   // V^T
    bf16* cb  = (bf16*)(ws + 73 * MB);   // ctx; high water 89 MB
    bf16* hb  = qb;                      // h reuses q (dead after attention)

    detect_k<<<1, 64, 0, stream>>>((const unsigned short*)x, flag);

    // one conversion dispatch: x | weights | mask+vectors
    conv_all_k<<<6153, 256, 0, stream>>>(x, Wq, Wk, Wv, Wo, mask,
                                         bq, bk, bv, bo, lnw, lnb,
                                         xb, wqb, maskf, bqf, bkf, bvf,
                                         bof, lnwf, lnbf, flag);

    dim3 gqkv(Hc / 128, Mc / 128, 3);
    qkv_gemm<<<gqkv, 256, 0, stream>>>(xb, wqb, bqf, wkb, bkf, wvb, bvf, qb, kb, vtb);
    attention<<<dim3(Bc * NHc * (Sc / 256)), 256, 0, stream>>>(qb, kb, vtb, maskf, cb);
    oproj_gemm<<<dim3(Hc / 128, Mc / 128), 256, 0, stream>>>(cb, wob, bof, xb, hb);
    layernorm_k<<<dim3(Mc), 256, 0, stream>>>(hb, lnwf, lnbf, d_out, flag);
}

// Round 7
// 338.804 us; speedup vs baseline: 1.0112x; 1.0062x over previous
//
#include <hip/hip_runtime.h>

typedef __bf16 bf16;
typedef __bf16 bf16x8 __attribute__((ext_vector_type(8)));
typedef __bf16 bf16x4 __attribute__((ext_vector_type(4)));
typedef float floatx4 __attribute__((ext_vector_type(4)));
typedef int   intx4  __attribute__((ext_vector_type(4)));
typedef int   intx2  __attribute__((ext_vector_type(2)));

#define MFMA16(a,b,c) __builtin_amdgcn_mfma_f32_16x16x32_bf16((a),(b),(c),0,0,0)

constexpr int Bc  = 4;
constexpr int Sc  = 2048;
constexpr int Hc  = 1024;
constexpr int NHc = 16;
constexpr int HDc = 64;
constexpr int Mc  = Bc * Sc;       // 8192 rows
constexpr int KIT = Hc / 32;       // 32 k-iterations
constexpr float L2E = 1.44269504088896f;

union U64  { bf16x4 h; intx2 i; };

// async global->LDS, 16B per lane (dest must be wave-uniform base + lane*16)
__device__ __forceinline__ void ld16(const bf16* g, bf16* l) {
    __builtin_amdgcn_global_load_lds(
        (const __attribute__((address_space(1))) void*)g,
        (__attribute__((address_space(3))) void*)l, 16, 0, 0);
}

// ---------------------------------------------------------------------------
// dtype detection (flag=1 -> inputs are fp32)
// ---------------------------------------------------------------------------
__global__ void detect_k(const unsigned short* __restrict__ x, int* __restrict__ flag)
{
    if (threadIdx.x == 0 && blockIdx.x == 0) {
        float mx = 0.f;
        for (int i = 0; i < 256; ++i) {
            unsigned int bits = ((unsigned int)x[i]) << 16;
            float v = __uint_as_float(bits);
            if (!isfinite(v)) { mx = 1e30f; break; }
            mx = fmaxf(mx, fabsf(v));
        }
        *flag = (mx > 1e6f) ? 1 : 0;
    }
}

// ---------------------------------------------------------------------------
// One merged conversion kernel: x (1048576 g8) | 4 weights (524288 g8) |
// mask+6 vectors (1792 g8)
// ---------------------------------------------------------------------------
__global__ __launch_bounds__(256)
void conv_all_k(const void* __restrict__ x,
                const void* __restrict__ Wq, const void* __restrict__ Wk,
                const void* __restrict__ Wv, const void* __restrict__ Wo,
                const void* __restrict__ mask,
                const void* __restrict__ bq, const void* __restrict__ bk,
                const void* __restrict__ bv, const void* __restrict__ bo,
                const void* __restrict__ lnw, const void* __restrict__ lnb,
                bf16* __restrict__ xb, bf16* __restrict__ wdst,
                float* maskf, float* bqf, float* bkf, float* bvf,
                float* bof, float* lnwf, float* lnbf,
                const int* __restrict__ flag)
{
    const int g = blockIdx.x * 256 + threadIdx.x;
    const int fl = *flag;
    if (g < 1048576) {
        if (fl) {
            const float* s = (const float*)x + (size_t)g * 8;
            union { intx4 v; bf16 e[8]; } o;
#pragma unroll
            for (int j = 0; j < 8; ++j) o.e[j] = (bf16)s[j];
            *(intx4*)(xb + (size_t)g * 8) = o.v;
        } else {
            *(intx4*)(xb + (size_t)g * 8) = *((const intx4*)x + g);
        }
    } else if (g < 1048576 + 524288) {
        const int gw = g - 1048576;
        const int wsel = gw >> 17, go = gw & 131071;
        const void* s = (wsel == 0) ? Wq : (wsel == 1) ? Wk : (wsel == 2) ? Wv : Wo;
        if (fl) {
            const float* sp = (const float*)s + (size_t)go * 8;
            union { intx4 v; bf16 e[8]; } o;
#pragma unroll
            for (int j = 0; j < 8; ++j) o.e[j] = (bf16)sp[j];
            *(intx4*)(wdst + (size_t)gw * 8) = o.v;
        } else {
            *(intx4*)(wdst + (size_t)gw * 8) = *((const intx4*)s + go);
        }
    } else {
        const int gs = g - 1048576 - 524288;
        if (gs >= 1792) return;
        const void* src; float* dst; int off; float scl = 1.0f;
        if (gs < 1024) { src = mask; dst = maskf; off = gs * 8; scl = L2E; }
        else {
            const int a = (gs - 1024) >> 7;
            off = ((gs - 1024) & 127) * 8;
            switch (a) {
                case 0: src = bq;  dst = bqf;  break;
                case 1: src = bk;  dst = bkf;  break;
                case 2: src = bv;  dst = bvf;  break;
                case 3: src = bo;  dst = bof;  break;
                case 4: src = lnw; dst = lnwf; break;
                default: src = lnb; dst = lnbf; break;
            }
        }
        if (fl) {
            const float* s = (const float*)src + off;
#pragma unroll
            for (int j = 0; j < 8; ++j) dst[off + j] = s[j] * scl;
        } else {
            union { intx4 v; bf16 e[8]; } u;
            u.v = *(const intx4*)((const bf16*)src + off);
#pragma unroll
            for (int j = 0; j < 8; ++j) dst[off + j] = (float)u.e[j] * scl;
        }
    }
}

// ---------------------------------------------------------------------------
// GEMM core: 128x128 tile over K=1024, A/W row-major.
// 2-phase pipelined: double-buffered LDS, stage(kb+1) issued BEFORE
// ds_read+MFMA of kb, ONE barrier per K-step.
// SWAP=0: acc[i][j] = C[xrow-block i][feat-block j]
// SWAP=1: acc[i][j] = C[feat-block j][xrow-block i] (lane cols = xrow)
// ---------------------------------------------------------------------------
template<int SWAP>
__device__ __forceinline__
void gemm_core(const bf16* __restrict__ A, const bf16* __restrict__ W,
               int m0, int n0, int t, bf16* As, bf16* Bs, floatx4 (&acc)[4][4])
{
    const int l  = t & 63, w = t >> 6;
    const int wr = w >> 1, wc = w & 1;
    const int lq = l >> 4, ln = l & 15;
    const int srow = t >> 2;            // 0..63
    const int scol = (t & 3) * 8;       // 0,8,16,24

    const bf16* a0 = A + (size_t)(m0 + srow) * Hc + scol;
    const bf16* b0 = W + (size_t)(n0 + srow) * Hc + scol;
    const int dst = srow * 32 + scol;   // lane-linear within a tile buffer

    auto stage = [&](int buf, int kb) {
        const int off = kb * 32;
        bf16* dA = As + buf * 4096;
        bf16* dB = Bs + buf * 4096;
        ld16(a0 + off,           dA + dst);
        ld16(a0 + 64 * Hc + off, dA + 64 * 32 + dst);
        ld16(b0 + off,           dB + dst);
        ld16(b0 + 64 * Hc + off, dB + 64 * 32 + dst);
    };

    stage(0, 0);
    int cur = 0;
    for (int kb = 0; kb < KIT; ++kb) {
        __syncthreads();                 // buf[cur] ready; buf[cur^1] readers done
        if (kb + 1 < KIT) stage(cur ^ 1, kb + 1);

        const bf16* Ab = As + cur * 4096;
        const bf16* Bb = Bs + cur * 4096;
        bf16x8 af[4], bw[4];
#pragma unroll
        for (int i = 0; i < 4; ++i)
            af[i] = *(const bf16x8*)&Ab[(wr * 64 + i * 16 + ln) * 32 + lq * 8];
#pragma unroll
        for (int j = 0; j < 4; ++j)
            bw[j] = *(const bf16x8*)&Bb[(wc * 64 + j * 16 + ln) * 32 + lq * 8];

        __builtin_amdgcn_s_setprio(1);
#pragma unroll
        for (int i = 0; i < 4; ++i)
#pragma unroll
            for (int j = 0; j < 4; ++j)
                acc[i][j] = SWAP ? MFMA16(bw[j], af[i], acc[i][j])
                                 : MFMA16(af[i], bw[j], acc[i][j]);
        __builtin_amdgcn_s_setprio(0);
        cur ^= 1;
    }
}

// chunked XCD remap for a (8 x 64) tile grid: each XCD owns 8 contiguous
// row-panels -> A-panel L2-resident per XCD, W fully L2-resident. Bijective.
__device__ __forceinline__ void xcd_remap(int bx, int by, int& m0, int& n0)
{
    const int flat = by * 8 + bx;            // dispatch-linear id, 0..511
    const int sw   = (flat & 7) * 64 + (flat >> 3);
    m0 = (sw >> 3) * 128;
    n0 = (sw & 7) * 128;
}

// ---------------------------------------------------------------------------
// Fused QKV: z=0 -> q (scaled by 0.125*log2e) [B,NH,S,HD]; z=1 -> k;
// z=2 -> V^T [B,NH,HD,S] via LDS transpose
// ---------------------------------------------------------------------------
__global__ __launch_bounds__(256)
void qkv_gemm(const bf16* __restrict__ x,
              const bf16* __restrict__ Wq, const float* __restrict__ bq,
              const bf16* __restrict__ Wk, const float* __restrict__ bk,
              const bf16* __restrict__ Wv, const float* __restrict__ bv,
              bf16* __restrict__ qo, bf16* __restrict__ ko, bf16* __restrict__ vto)
{
    __shared__ __align__(16) bf16 smem[16384];  // 2 x (2x4096) dbuf; Ct reuse
    const int z = blockIdx.z;
    const bf16*  W    = (z == 0) ? Wq : (z == 1) ? Wk : Wv;
    const float* bias = (z == 0) ? bq : (z == 1) ? bk : bv;

    int m0, n0;
    xcd_remap(blockIdx.x, blockIdx.y, m0, n0);
    const int t  = threadIdx.x;
    const int l  = t & 63, w = t >> 6;
    const int wr = w >> 1, wc = w & 1;
    const int lq = l >> 4, ln = l & 15;

    if (z < 2) {
        floatx4 acc[4][4] = {};
        gemm_core<1>(x, W, m0, n0, t, smem, smem + 8192, acc);
        bf16* out = (z == 0) ? qo : ko;
        const float sc = (z == 0) ? 0.125f * L2E : 1.0f;
#pragma unroll
        for (int j = 0; j < 4; ++j) {
            const int feat = n0 + wc * 64 + j * 16 + lq * 4;   // 4 consecutive
            const floatx4 bb = *(const floatx4*)&bias[feat];
            const int hh = feat >> 6, dd = feat & 63;
#pragma unroll
            for (int i = 0; i < 4; ++i) {
                const int xrow = m0 + wr * 64 + i * 16 + ln;
                const int bi = xrow >> 11, si = xrow & (Sc - 1);
                U64 pk;
#pragma unroll
                for (int r = 0; r < 4; ++r) pk.h[r] = (bf16)((acc[i][j][r] + bb[r]) * sc);
                *(intx2*)&out[(((size_t)bi * NHc + hh) * Sc + si) * HDc + dd] = pk.i;
            }
        }
    } else {
        floatx4 acc[4][4] = {};
        gemm_core<0>(x, W, m0, n0, t, smem, smem + 8192, acc);
        // transpose epilogue: Ct[64 cols][136 rows], two col-halves
        bf16* Ct = smem;
        const int bi = m0 >> 11, s0 = m0 & (Sc - 1);
        for (int h2 = 0; h2 < 2; ++h2) {
            __syncthreads();
            if (wc == h2) {
#pragma unroll
                for (int j = 0; j < 4; ++j) {
                    const int c = j * 16 + ln;
                    const float bb = bias[n0 + h2 * 64 + c];
#pragma unroll
                    for (int i = 0; i < 4; ++i) {
                        U64 pk;
#pragma unroll
                        for (int r = 0; r < 4; ++r) pk.h[r] = (bf16)(acc[i][j][r] + bb);
                        *(intx2*)&Ct[c * 136 + wr * 64 + i * 16 + lq * 4] = pk.i;
                    }
                }
            }
            __syncthreads();
#pragma unroll
            for (int u = 0; u < 4; ++u) {
                const int id = t + 256 * u;           // 0..1023
                const int c = id >> 4, rg = id & 15;
                const int hh = (n0 >> 6) + h2;
                intx4 val = *(const intx4*)&Ct[c * 136 + rg * 8];
                *(intx4*)&vto[(((size_t)bi * NHc + hh) * HDc + c) * Sc + s0 + rg * 8] = val;
            }
        }
    }
}

// ---------------------------------------------------------------------------
// Output projection + bias + residual -> h (bf16), b64 loads/stores
// ---------------------------------------------------------------------------
__global__ __launch_bounds__(256)
void oproj_gemm(const bf16* __restrict__ ctx, const bf16* __restrict__ Wo,
                const float* __restrict__ bo, const bf16* __restrict__ xb,
                bf16* __restrict__ hout)
{
    __shared__ __align__(16) bf16 smem[16384];
    int m0, n0;
    xcd_remap(blockIdx.x, blockIdx.y, m0, n0);
    const int t  = threadIdx.x;
    floatx4 acc[4][4] = {};
    gemm_core<1>(ctx, Wo, m0, n0, t, smem, smem + 8192, acc);

    const int l  = t & 63, w = t >> 6;
    const int wr = w >> 1, wc = w & 1;
    const int lq = l >> 4, ln = l & 15;
#pragma unroll
    for (int j = 0; j < 4; ++j) {
        const int col = n0 + wc * 64 + j * 16 + lq * 4;   // 4 consecutive
        const floatx4 bb = *(const floatx4*)&bo[col];
#pragma unroll
        for (int i = 0; i < 4; ++i) {
            const int row = m0 + wr * 64 + i * 16 + ln;
            U64 rx;
            rx.i = *(const intx2*)&xb[(size_t)row * Hc + col];
            U64 pk;
#pragma unroll
            for (int r = 0; r < 4; ++r)
                pk.h[r] = (bf16)(acc[i][j][r] + bb[r] + (float)rx.h[r]);
            *(intx2*)&hout[(size_t)row * Hc + col] = pk.i;
        }
    }
}

// ---------------------------------------------------------------------------
// Flash attention, S^T formulation, fixed-max softmax.
// 1 WG = 4 waves x 64 q-rows = 256 q-rows (R0's proven-best shape/dataflow),
// with every LDS-pipe waste surgically removed:
//   - K AND V staged via global_load_lds DMA double-buffer with XOR-swizzle
//     (pre-swizzled global source, lane-linear LDS dest; R4-proven correct):
//     removes 4 ds_write_b128/lane/tile, kf/vf reads conflict-free,
//     ONE barrier per tile.
//   - Pt XOR-swizzled [4][64][64]: granule g of row r stored at g^(2*(r&7)).
//     b64 writes <=2-way (free), b128 pf reads conflict-free (same bank
//     distribution as the proven kf pattern). Replaces pad-72 (4-way reads).
//   - denominator: f32 adds in softmax + 2 final shfl_xor (no ones-MFMA):
//     64 MFMA/tile/wave instead of 72.
// Register discipline: per-qb chaining (s[4] transient) -- no spills.
// LDS: 16K Ks + 16K Vs + 32K Pt = 64 KB -> 2 blocks/CU.
// ---------------------------------------------------------------------------
__global__ __launch_bounds__(256, 2)
void attention(const bf16* __restrict__ q, const bf16* __restrict__ k,
               const bf16* __restrict__ vt, const float* __restrict__ maskf,
               bf16* __restrict__ ctx)
{
    __shared__ __align__(16) bf16 Ks[2][64][64];   // [dbuf][kpos][hd] swizzled
    __shared__ __align__(16) bf16 Vs[2][64][64];   // [dbuf][d][kpos] swizzled
    __shared__ __align__(16) bf16 Pt[4][64][64];   // [wave][qrow][kpos] swizzled

    // XCD-aware remap: raw%8 = XCD; 8 consecutive (b,h) per XCD. 512%8==0.
    const int raw = blockIdx.x;                 // 0..511
    const int xcd = raw & 7, jj = raw >> 3;     // jj 0..63
    const int bh  = xcd * 8 + (jj >> 3);
    const int qt  = jj & 7;                     // q-tile of 256 rows
    const int b = bh >> 4, h = bh & 15;
    const int t = threadIdx.x, w = t >> 6, l = t & 63;
    const int lq = l >> 4, ln = l & 15;
    const int q0 = qt * 256 + w * 64;

    const bf16* kg = k  + (size_t)bh * Sc * HDc;
    const bf16* vg = vt + (size_t)bh * HDc * Sc;
    const float* mbase = maskf + b * Sc;        // pre-scaled by log2e

    // DMA staging geometry (R4-proven): wave w covers rows [16w,16w+16) in
    // two 8-row calls; dest is lane-linear; LDS granule c of row r holds
    // global granule c^(r&7) via pre-swizzled global source column.
    const int rr  = l >> 3;
    const int gsw = ((l & 7) ^ rr) << 3;        // pre-swizzled global col (elems)
    const int r0  = w * 16 + rr, r1 = r0 + 8;
    const int dco = (l & 7) << 3;               // lane-linear LDS col (elems)
    const int sw  = ln & 7;                     // K/V read-side swizzle key
    const int pkey = sw << 1;                   // Pt granule XOR key (even)

    // Q fragments in registers (B-operand); q pre-scaled by 0.125*log2e
    bf16x8 qf[4][2];
#pragma unroll
    for (int qb = 0; qb < 4; ++qb)
#pragma unroll
        for (int kh = 0; kh < 2; ++kh)
            qf[qb][kh] = *(const bf16x8*)(q + ((size_t)bh * Sc + q0 + qb * 16 + ln) * HDc
                                            + kh * 32 + lq * 8);

    floatx4 o[4][4] = {};
    float dacc[4] = {0.f, 0.f, 0.f, 0.f};

    auto stage = [&](int buf, int kt) {
        bf16* Kd = &Ks[buf][0][0];
        bf16* Vd = &Vs[buf][0][0];
        ld16(kg + (size_t)(kt * 64 + r0) * HDc + gsw, Kd + r0 * 64 + dco);
        ld16(kg + (size_t)(kt * 64 + r1) * HDc + gsw, Kd + r1 * 64 + dco);
        ld16(vg + (size_t)r0 * Sc + kt * 64 + gsw,    Vd + r0 * 64 + dco);
        ld16(vg + (size_t)r1 * Sc + kt * 64 + gsw,    Vd + r1 * 64 + dco);
    };

    stage(0, 0);
    int cur = 0;
    bf16* PtW = &Pt[w][0][0];                   // wave-private rows

    for (int kt = 0; kt < Sc / 64; ++kt) {
        __syncthreads();                 // drains own vmcnt -> buf[cur] ready
        if (kt + 1 < Sc / 64) stage(cur ^ 1, kt + 1);

        // mask (log2 domain): QK^T accumulator init (free add)
        floatx4 mvl[4];
#pragma unroll
        for (int cb = 0; cb < 4; ++cb)
            mvl[cb] = *(const floatx4*)(mbase + kt * 64 + cb * 16 + lq * 4);

        // K fragments once per tile, swizzled reads (conflict-free)
        bf16x8 kf[4][2];
#pragma unroll
        for (int cb = 0; cb < 4; ++cb)
#pragma unroll
            for (int kh = 0; kh < 2; ++kh)
                kf[cb][kh] = *(const bf16x8*)&Ks[cur][cb * 16 + ln]
                                               [((kh * 4 + lq) ^ sw) << 3];

        // per q-block: S^T = K*Q^T + mask -> exp2 -> swizzled Pt write
#pragma unroll
        for (int qb = 0; qb < 4; ++qb) {
            floatx4 s[4];
#pragma unroll
            for (int cb = 0; cb < 4; ++cb) s[cb] = mvl[cb];
            __builtin_amdgcn_s_setprio(1);
#pragma unroll
            for (int kh = 0; kh < 2; ++kh)
#pragma unroll
                for (int cb = 0; cb < 4; ++cb)
                    s[cb] = MFMA16(kf[cb][kh], qf[qb][kh], s[cb]);
            __builtin_amdgcn_s_setprio(0);
            float ds = 0.f;
#pragma unroll
            for (int cb = 0; cb < 4; ++cb) {
                U64 pk;
#pragma unroll
                for (int r = 0; r < 4; ++r) {
                    const float e = __builtin_amdgcn_exp2f(s[cb][r]);
                    ds += e;
                    pk.h[r] = (bf16)e;
                }
                // logical granule cb*4+lq (8B) -> phys granule ^(pkey)
                *(intx2*)(PtW + (qb * 16 + ln) * 64
                              + (((cb * 4 + lq) ^ pkey) << 2)) = pk.i;
            }
            dacc[qb] += ds;
        }

        // V fragments once per tile, swizzled reads (conflict-free)
        bf16x8 vf[4][2];
#pragma unroll
        for (int db = 0; db < 4; ++db)
#pragma unroll
            for (int kh = 0; kh < 2; ++kh)
                vf[db][kh] = *(const bf16x8*)&Vs[cur][db * 16 + ln]
                                               [((kh * 4 + lq) ^ sw) << 3];

        // per q-block: O^T += V^T * P^T ; pf reads de-swizzle Pt
#pragma unroll
        for (int qb = 0; qb < 4; ++qb) {
            const bf16x8 pf0 = *(const bf16x8*)(PtW + (qb * 16 + ln) * 64
                                                    + (((2 * lq) ^ pkey) << 2));
            const bf16x8 pf1 = *(const bf16x8*)(PtW + (qb * 16 + ln) * 64
                                                    + (((8 + 2 * lq) ^ pkey) << 2));
            __builtin_amdgcn_s_setprio(1);
#pragma unroll
            for (int db = 0; db < 4; ++db) {
                o[qb][db] = MFMA16(vf[db][0], pf0, o[qb][db]);
                o[qb][db] = MFMA16(vf[db][1], pf1, o[qb][db]);
            }
            __builtin_amdgcn_s_setprio(0);
        }
        cur ^= 1;
    }

    // finish denominators (sum over the 4-lane stride-16 group), store ctx
#pragma unroll
    for (int qb = 0; qb < 4; ++qb) {
        float dsum = dacc[qb];
        dsum += __shfl_xor(dsum, 16, 64);
        dsum += __shfl_xor(dsum, 32, 64);
        const float li = 1.f / dsum;
        const int qg = q0 + qb * 16 + ln;
#pragma unroll
        for (int db = 0; db < 4; ++db) {
            U64 pk;
#pragma unroll
            for (int r = 0; r < 4; ++r) pk.h[r] = (bf16)(o[qb][db][r] * li);
            *(intx2*)&ctx[((size_t)b * Sc + qg) * Hc + h * HDc + db * 16 + lq * 4] = pk.i;
        }
    }
}

// ---------------------------------------------------------------------------
// LayerNorm; output dtype keyed off flag
// ---------------------------------------------------------------------------
__global__ __launch_bounds__(256)
void layernorm_k(const bf16* __restrict__ hbuf, const float* __restrict__ lw,
                 const float* __restrict__ lb, void* __restrict__ outp,
                 const int* __restrict__ flag)
{
    const int row = blockIdx.x;
    const int t = threadIdx.x;
    const bf16* hp = hbuf + (size_t)row * Hc;

    union { intx2 i2; bf16 e[4]; } pk;
    pk.i2 = *(const intx2*)(hp + t * 4);
    float v[4], sum = 0.f, sq = 0.f;
#pragma unroll
    for (int i = 0; i < 4; ++i) {
        v[i] = (float)pk.e[i];
        sum += v[i];
        sq  += v[i] * v[i];
    }
#pragma unroll
    for (int off = 1; off < 64; off <<= 1) {
        sum += __shfl_xor(sum, off, 64);
        sq  += __shfl_xor(sq,  off, 64);
    }
    __shared__ float ssum[4], ssq[4];
    const int w = t >> 6;
    if ((t & 63) == 0) { ssum[w] = sum; ssq[w] = sq; }
    __syncthreads();
    sum = ssum[0] + ssum[1] + ssum[2] + ssum[3];
    sq  = ssq[0]  + ssq[1]  + ssq[2]  + ssq[3];

    const float mean = sum * (1.f / (float)Hc);
    const float var  = sq * (1.f / (float)Hc) - mean * mean;
    const float rstd = rsqrtf(var + 1e-12f);

    float ov[4];
#pragma unroll
    for (int i = 0; i < 4; ++i) {
        const int c = t * 4 + i;
        ov[i] = lw[c] * (v[i] - mean) * rstd + lb[c];
    }
    if (*flag) {
        float* of = (float*)outp + (size_t)row * Hc + t * 4;
#pragma unroll
        for (int i = 0; i < 4; ++i) of[i] = ov[i];
    } else {
        union { intx2 i2; bf16 e[4]; } po;
#pragma unroll
        for (int i = 0; i < 4; ++i) po.e[i] = (bf16)ov[i];
        *(intx2*)((bf16*)outp + (size_t)row * Hc + t * 4) = po.i2;
    }
}

// ---------------------------------------------------------------------------
extern "C" void kernel_launch(void* const* d_in, const int* in_sizes, int n_in,
                              void* d_out, int out_size, void* d_ws, size_t ws_size,
                              hipStream_t stream)
{
    const void* x    = d_in[0];
    const void* mask = d_in[1];
    const void* Wq   = d_in[2];
    const void* bq   = d_in[3];
    const void* Wk   = d_in[4];
    const void* bk   = d_in[5];
    const void* Wv   = d_in[6];
    const void* bv   = d_in[7];
    const void* Wo   = d_in[8];
    const void* bo   = d_in[9];
    const void* lnw  = d_in[10];
    const void* lnb  = d_in[11];

    char* ws = (char*)d_ws;
    const size_t MB = 1024 * 1024;
    int*   flag  = (int*)ws;
    float* maskf = (float*)(ws + 4096);
    float* bqf   = (float*)(ws + 64 * 1024);
    float* bkf   = bqf + Hc;
    float* bvf   = bkf + Hc;
    float* bof   = bvf + Hc;
    float* lnwf  = bof + Hc;
    float* lnbf  = lnwf + Hc;
    bf16* xb  = (bf16*)(ws + 1 * MB);    // 16 MB
    bf16* wqb = (bf16*)(ws + 17 * MB);   // 2 MB each, contiguous wq|wk|wv|wo
    bf16* wkb = (bf16*)(ws + 19 * MB);
    bf16* wvb = (bf16*)(ws + 21 * MB);
    bf16* wob = (bf16*)(ws + 23 * MB);
    bf16* qb  = (bf16*)(ws + 25 * MB);   // 16 MB
    bf16* kb  = (bf16*)(ws + 41 * MB);
    bf16* vtb = (bf16*)(ws + 57 * MB);   // V^T
    bf16* cb  = (bf16*)(ws + 73 * MB);   // ctx; high water 89 MB
    bf16* hb  = qb;                      // h reuses q (dead after attention)

    detect_k<<<1, 64, 0, stream>>>((const unsigned short*)x, flag);

    // one conversion dispatch: x | weights | mask+vectors
    conv_all_k<<<6153, 256, 0, stream>>>(x, Wq, Wk, Wv, Wo, mask,
                                         bq, bk, bv, bo, lnw, lnb,
                                         xb, wqb, maskf, bqf, bkf, bvf,
                                         bof, lnwf, lnbf, flag);

    dim3 gqkv(Hc / 128, Mc / 128, 3);
    qkv_gemm<<<gqkv, 256, 0, stream>>>(xb, wqb, bqf, wkb, bkf, wvb, bvf, qb, kb, vtb);
    attention<<<dim3(Bc * NHc * (Sc / 256)), 256, 0, stream>>>(qb, kb, vtb, maskf, cb);
    oproj_gemm<<<dim3(Hc / 128, Mc / 128), 256, 0, stream>>>(cb, wob, bof, xb, hb);
    layernorm_k<<<dim3(Mc), 256, 0, stream>>>(hb, lnwf, lnbf, d_out, flag);
}

// Round 8
// 288.171 us; speedup vs baseline: 1.1889x; 1.1757x over previous
//
#include <hip/hip_runtime.h>

typedef __bf16 bf16;
typedef __bf16 bf16x8 __attribute__((ext_vector_type(8)));
typedef __bf16 bf16x4 __attribute__((ext_vector_type(4)));
typedef float floatx4 __attribute__((ext_vector_type(4)));
typedef int   intx4  __attribute__((ext_vector_type(4)));
typedef int   intx2  __attribute__((ext_vector_type(2)));

#define MFMA16(a,b,c) __builtin_amdgcn_mfma_f32_16x16x32_bf16((a),(b),(c),0,0,0)

constexpr int Bc  = 4;
constexpr int Sc  = 2048;
constexpr int Hc  = 1024;
constexpr int NHc = 16;
constexpr int HDc = 64;
constexpr int Mc  = Bc * Sc;       // 8192 rows
constexpr int KIT = Hc / 32;       // 32 k-iterations
constexpr float L2E = 1.44269504088896f;

union U64  { bf16x4 h; intx2 i; };

// async global->LDS, 16B per lane (dest must be wave-uniform base + lane*16)
__device__ __forceinline__ void ld16(const bf16* g, bf16* l) {
    __builtin_amdgcn_global_load_lds(
        (const __attribute__((address_space(1))) void*)g,
        (__attribute__((address_space(3))) void*)l, 16, 0, 0);
}

// ---------------------------------------------------------------------------
// Inline per-block dtype detect (replaces the old serial 1-thread detect_k):
// 256 threads read the first 256 ushorts of x (512B, L2-broadcast after the
// first block), treat each as a truncated fp32, reduce-max wave-parallel.
// Semantics identical to the serial loop: non-finite -> 1e30 -> flag=1;
// flag = (max > 1e6).  ~300 cy per block.
// ---------------------------------------------------------------------------
__device__ __forceinline__ int detect_flag_block(const void* x, float* wmx)
{
    const unsigned short* xs = (const unsigned short*)x;
    const int tt = threadIdx.x;            // 256 threads, one value each
    unsigned int bits = ((unsigned int)xs[tt]) << 16;
    float v = __uint_as_float(bits);
    float a = isfinite(v) ? fabsf(v) : 1e30f;
#pragma unroll
    for (int off = 1; off < 64; off <<= 1)
        a = fmaxf(a, __shfl_xor(a, off, 64));
    if ((tt & 63) == 0) wmx[tt >> 6] = a;
    __syncthreads();
    const float m = fmaxf(fmaxf(wmx[0], wmx[1]), fmaxf(wmx[2], wmx[3]));
    __syncthreads();                       // wmx reusable after this
    return (m > 1e6f) ? 1 : 0;
}

// ---------------------------------------------------------------------------
// One merged conversion kernel: x (1048576 g8) | 4 weights (524288 g8) |
// mask+6 vectors (1792 g8)
// ---------------------------------------------------------------------------
__global__ __launch_bounds__(256)
void conv_all_k(const void* __restrict__ x,
                const void* __restrict__ Wq, const void* __restrict__ Wk,
                const void* __restrict__ Wv, const void* __restrict__ Wo,
                const void* __restrict__ mask,
                const void* __restrict__ bq, const void* __restrict__ bk,
                const void* __restrict__ bv, const void* __restrict__ bo,
                const void* __restrict__ lnw, const void* __restrict__ lnb,
                bf16* __restrict__ xb, bf16* __restrict__ wdst,
                float* maskf, float* bqf, float* bkf, float* bvf,
                float* bof, float* lnwf, float* lnbf)
{
    __shared__ float wmx[4];
    const int fl = detect_flag_block(x, wmx);

    const int g = blockIdx.x * 256 + threadIdx.x;
    if (g < 1048576) {
        if (fl) {
            const float* s = (const float*)x + (size_t)g * 8;
            union { intx4 v; bf16 e[8]; } o;
#pragma unroll
            for (int j = 0; j < 8; ++j) o.e[j] = (bf16)s[j];
            *(intx4*)(xb + (size_t)g * 8) = o.v;
        } else {
            *(intx4*)(xb + (size_t)g * 8) = *((const intx4*)x + g);
        }
    } else if (g < 1048576 + 524288) {
        const int gw = g - 1048576;
        const int wsel = gw >> 17, go = gw & 131071;
        const void* s = (wsel == 0) ? Wq : (wsel == 1) ? Wk : (wsel == 2) ? Wv : Wo;
        if (fl) {
            const float* sp = (const float*)s + (size_t)go * 8;
            union { intx4 v; bf16 e[8]; } o;
#pragma unroll
            for (int j = 0; j < 8; ++j) o.e[j] = (bf16)sp[j];
            *(intx4*)(wdst + (size_t)gw * 8) = o.v;
        } else {
            *(intx4*)(wdst + (size_t)gw * 8) = *((const intx4*)s + go);
        }
    } else {
        const int gs = g - 1048576 - 524288;
        if (gs >= 1792) return;
        const void* src; float* dst; int off; float scl = 1.0f;
        if (gs < 1024) { src = mask; dst = maskf; off = gs * 8; scl = L2E; }
        else {
            const int a = (gs - 1024) >> 7;
            off = ((gs - 1024) & 127) * 8;
            switch (a) {
                case 0: src = bq;  dst = bqf;  break;
                case 1: src = bk;  dst = bkf;  break;
                case 2: src = bv;  dst = bvf;  break;
                case 3: src = bo;  dst = bof;  break;
                case 4: src = lnw; dst = lnwf; break;
                default: src = lnb; dst = lnbf; break;
            }
        }
        if (fl) {
            const float* s = (const float*)src + off;
#pragma unroll
            for (int j = 0; j < 8; ++j) dst[off + j] = s[j] * scl;
        } else {
            union { intx4 v; bf16 e[8]; } u;
            u.v = *(const intx4*)((const bf16*)src + off);
#pragma unroll
            for (int j = 0; j < 8; ++j) dst[off + j] = (float)u.e[j] * scl;
        }
    }
}

// ---------------------------------------------------------------------------
// GEMM core: 128x128 tile over K=1024, A/W row-major.
// 2-phase pipelined: double-buffered LDS, stage(kb+1) issued BEFORE
// ds_read+MFMA of kb, ONE barrier per K-step.
// SWAP=0: acc[i][j] = C[xrow-block i][feat-block j]
// SWAP=1: acc[i][j] = C[feat-block j][xrow-block i] (lane cols = xrow)
// ---------------------------------------------------------------------------
template<int SWAP>
__device__ __forceinline__
void gemm_core(const bf16* __restrict__ A, const bf16* __restrict__ W,
               int m0, int n0, int t, bf16* As, bf16* Bs, floatx4 (&acc)[4][4])
{
    const int l  = t & 63, w = t >> 6;
    const int wr = w >> 1, wc = w & 1;
    const int lq = l >> 4, ln = l & 15;
    const int srow = t >> 2;            // 0..63
    const int scol = (t & 3) * 8;       // 0,8,16,24

    const bf16* a0 = A + (size_t)(m0 + srow) * Hc + scol;
    const bf16* b0 = W + (size_t)(n0 + srow) * Hc + scol;
    const int dst = srow * 32 + scol;   // lane-linear within a tile buffer

    auto stage = [&](int buf, int kb) {
        const int off = kb * 32;
        bf16* dA = As + buf * 4096;
        bf16* dB = Bs + buf * 4096;
        ld16(a0 + off,           dA + dst);
        ld16(a0 + 64 * Hc + off, dA + 64 * 32 + dst);
        ld16(b0 + off,           dB + dst);
        ld16(b0 + 64 * Hc + off, dB + 64 * 32 + dst);
    };

    stage(0, 0);
    int cur = 0;
    for (int kb = 0; kb < KIT; ++kb) {
        __syncthreads();                 // buf[cur] ready; buf[cur^1] readers done
        if (kb + 1 < KIT) stage(cur ^ 1, kb + 1);

        const bf16* Ab = As + cur * 4096;
        const bf16* Bb = Bs + cur * 4096;
        bf16x8 af[4], bw[4];
#pragma unroll
        for (int i = 0; i < 4; ++i)
            af[i] = *(const bf16x8*)&Ab[(wr * 64 + i * 16 + ln) * 32 + lq * 8];
#pragma unroll
        for (int j = 0; j < 4; ++j)
            bw[j] = *(const bf16x8*)&Bb[(wc * 64 + j * 16 + ln) * 32 + lq * 8];

        __builtin_amdgcn_s_setprio(1);
#pragma unroll
        for (int i = 0; i < 4; ++i)
#pragma unroll
            for (int j = 0; j < 4; ++j)
                acc[i][j] = SWAP ? MFMA16(bw[j], af[i], acc[i][j])
                                 : MFMA16(af[i], bw[j], acc[i][j]);
        __builtin_amdgcn_s_setprio(0);
        cur ^= 1;
    }
}

// chunked XCD remap for a (8 x 64) tile grid: each XCD owns 8 contiguous
// row-panels -> A-panel L2-resident per XCD, W fully L2-resident. Bijective.
__device__ __forceinline__ void xcd_remap(int bx, int by, int& m0, int& n0)
{
    const int flat = by * 8 + bx;            // dispatch-linear id, 0..511
    const int sw   = (flat & 7) * 64 + (flat >> 3);
    m0 = (sw >> 3) * 128;
    n0 = (sw & 7) * 128;
}

// ---------------------------------------------------------------------------
// Fused QKV: z=0 -> q (scaled by 0.125*log2e) [B,NH,S,HD]; z=1 -> k;
// z=2 -> V^T [B,NH,HD,S] via LDS transpose
// launch_bounds(256,3): VGPR cap ~170 (est. use ~130) -> 3 blocks/CU for
// extra TLP over the per-K-step DMA drain (was 2).
// ---------------------------------------------------------------------------
__global__ __launch_bounds__(256, 3)
void qkv_gemm(const bf16* __restrict__ x,
              const bf16* __restrict__ Wq, const float* __restrict__ bq,
              const bf16* __restrict__ Wk, const float* __restrict__ bk,
              const bf16* __restrict__ Wv, const float* __restrict__ bv,
              bf16* __restrict__ qo, bf16* __restrict__ ko, bf16* __restrict__ vto)
{
    __shared__ __align__(16) bf16 smem[16384];  // 2 x (2x4096) dbuf; Ct reuse
    const int z = blockIdx.z;
    const bf16*  W    = (z == 0) ? Wq : (z == 1) ? Wk : Wv;
    const float* bias = (z == 0) ? bq : (z == 1) ? bk : bv;

    int m0, n0;
    xcd_remap(blockIdx.x, blockIdx.y, m0, n0);
    const int t  = threadIdx.x;
    const int l  = t & 63, w = t >> 6;
    const int wr = w >> 1, wc = w & 1;
    const int lq = l >> 4, ln = l & 15;

    if (z < 2) {
        floatx4 acc[4][4] = {};
        gemm_core<1>(x, W, m0, n0, t, smem, smem + 8192, acc);
        bf16* out = (z == 0) ? qo : ko;
        const float sc = (z == 0) ? 0.125f * L2E : 1.0f;
#pragma unroll
        for (int j = 0; j < 4; ++j) {
            const int feat = n0 + wc * 64 + j * 16 + lq * 4;   // 4 consecutive
            const floatx4 bb = *(const floatx4*)&bias[feat];
            const int hh = feat >> 6, dd = feat & 63;
#pragma unroll
            for (int i = 0; i < 4; ++i) {
                const int xrow = m0 + wr * 64 + i * 16 + ln;
                const int bi = xrow >> 11, si = xrow & (Sc - 1);
                U64 pk;
#pragma unroll
                for (int r = 0; r < 4; ++r) pk.h[r] = (bf16)((acc[i][j][r] + bb[r]) * sc);
                *(intx2*)&out[(((size_t)bi * NHc + hh) * Sc + si) * HDc + dd] = pk.i;
            }
        }
    } else {
        floatx4 acc[4][4] = {};
        gemm_core<0>(x, W, m0, n0, t, smem, smem + 8192, acc);
        // transpose epilogue: Ct[64 cols][136 rows], two col-halves
        bf16* Ct = smem;
        const int bi = m0 >> 11, s0 = m0 & (Sc - 1);
        for (int h2 = 0; h2 < 2; ++h2) {
            __syncthreads();
            if (wc == h2) {
#pragma unroll
                for (int j = 0; j < 4; ++j) {
                    const int c = j * 16 + ln;
                    const float bb = bias[n0 + h2 * 64 + c];
#pragma unroll
                    for (int i = 0; i < 4; ++i) {
                        U64 pk;
#pragma unroll
                        for (int r = 0; r < 4; ++r) pk.h[r] = (bf16)(acc[i][j][r] + bb);
                        *(intx2*)&Ct[c * 136 + wr * 64 + i * 16 + lq * 4] = pk.i;
                    }
                }
            }
            __syncthreads();
#pragma unroll
            for (int u = 0; u < 4; ++u) {
                const int id = t + 256 * u;           // 0..1023
                const int c = id >> 4, rg = id & 15;
                const int hh = (n0 >> 6) + h2;
                intx4 val = *(const intx4*)&Ct[c * 136 + rg * 8];
                *(intx4*)&vto[(((size_t)bi * NHc + hh) * HDc + c) * Sc + s0 + rg * 8] = val;
            }
        }
    }
}

// ---------------------------------------------------------------------------
// Output projection + bias + residual -> h (bf16), b64 loads/stores
// ---------------------------------------------------------------------------
__global__ __launch_bounds__(256, 3)
void oproj_gemm(const bf16* __restrict__ ctx, const bf16* __restrict__ Wo,
                const float* __restrict__ bo, const bf16* __restrict__ xb,
                bf16* __restrict__ hout)
{
    __shared__ __align__(16) bf16 smem[16384];
    int m0, n0;
    xcd_remap(blockIdx.x, blockIdx.y, m0, n0);
    const int t  = threadIdx.x;
    floatx4 acc[4][4] = {};
    gemm_core<1>(ctx, Wo, m0, n0, t, smem, smem + 8192, acc);

    const int l  = t & 63, w = t >> 6;
    const int wr = w >> 1, wc = w & 1;
    const int lq = l >> 4, ln = l & 15;
#pragma unroll
    for (int j = 0; j < 4; ++j) {
        const int col = n0 + wc * 64 + j * 16 + lq * 4;   // 4 consecutive
        const floatx4 bb = *(const floatx4*)&bo[col];
#pragma unroll
        for (int i = 0; i < 4; ++i) {
            const int row = m0 + wr * 64 + i * 16 + ln;
            U64 rx;
            rx.i = *(const intx2*)&xb[(size_t)row * Hc + col];
            U64 pk;
#pragma unroll
            for (int r = 0; r < 4; ++r)
                pk.h[r] = (bf16)(acc[i][j][r] + bb[r] + (float)rx.h[r]);
            *(intx2*)&hout[(size_t)row * Hc + col] = pk.i;
        }
    }
}

// ---------------------------------------------------------------------------
// Flash attention, S^T formulation, fixed-max softmax.  (R7, unchanged --
// verified 94.6us; structure at its local minimum per R0/R1/R4/R7 data.)
// ---------------------------------------------------------------------------
__global__ __launch_bounds__(256, 2)
void attention(const bf16* __restrict__ q, const bf16* __restrict__ k,
               const bf16* __restrict__ vt, const float* __restrict__ maskf,
               bf16* __restrict__ ctx)
{
    __shared__ __align__(16) bf16 Ks[2][64][64];   // [dbuf][kpos][hd] swizzled
    __shared__ __align__(16) bf16 Vs[2][64][64];   // [dbuf][d][kpos] swizzled
    __shared__ __align__(16) bf16 Pt[4][64][64];   // [wave][qrow][kpos] swizzled

    // XCD-aware remap: raw%8 = XCD; 8 consecutive (b,h) per XCD. 512%8==0.
    const int raw = blockIdx.x;                 // 0..511
    const int xcd = raw & 7, jj = raw >> 3;     // jj 0..63
    const int bh  = xcd * 8 + (jj >> 3);
    const int qt  = jj & 7;                     // q-tile of 256 rows
    const int b = bh >> 4, h = bh & 15;
    const int t = threadIdx.x, w = t >> 6, l = t & 63;
    const int lq = l >> 4, ln = l & 15;
    const int q0 = qt * 256 + w * 64;

    const bf16* kg = k  + (size_t)bh * Sc * HDc;
    const bf16* vg = vt + (size_t)bh * HDc * Sc;
    const float* mbase = maskf + b * Sc;        // pre-scaled by log2e

    // DMA staging geometry: wave w covers rows [16w,16w+16) in two 8-row
    // calls; dest lane-linear; LDS granule c of row r holds global granule
    // c^(r&7) via pre-swizzled global source column.
    const int rr  = l >> 3;
    const int gsw = ((l & 7) ^ rr) << 3;        // pre-swizzled global col (elems)
    const int r0  = w * 16 + rr, r1 = r0 + 8;
    const int dco = (l & 7) << 3;               // lane-linear LDS col (elems)
    const int sw  = ln & 7;                     // K/V read-side swizzle key
    const int pkey = sw << 1;                   // Pt granule XOR key (even)

    // Q fragments in registers (B-operand); q pre-scaled by 0.125*log2e
    bf16x8 qf[4][2];
#pragma unroll
    for (int qb = 0; qb < 4; ++qb)
#pragma unroll
        for (int kh = 0; kh < 2; ++kh)
            qf[qb][kh] = *(const bf16x8*)(q + ((size_t)bh * Sc + q0 + qb * 16 + ln) * HDc
                                            + kh * 32 + lq * 8);

    floatx4 o[4][4] = {};
    float dacc[4] = {0.f, 0.f, 0.f, 0.f};

    auto stage = [&](int buf, int kt) {
        bf16* Kd = &Ks[buf][0][0];
        bf16* Vd = &Vs[buf][0][0];
        ld16(kg + (size_t)(kt * 64 + r0) * HDc + gsw, Kd + r0 * 64 + dco);
        ld16(kg + (size_t)(kt * 64 + r1) * HDc + gsw, Kd + r1 * 64 + dco);
        ld16(vg + (size_t)r0 * Sc + kt * 64 + gsw,    Vd + r0 * 64 + dco);
        ld16(vg + (size_t)r1 * Sc + kt * 64 + gsw,    Vd + r1 * 64 + dco);
    };

    stage(0, 0);
    int cur = 0;
    bf16* PtW = &Pt[w][0][0];                   // wave-private rows

    for (int kt = 0; kt < Sc / 64; ++kt) {
        __syncthreads();                 // drains own vmcnt -> buf[cur] ready
        if (kt + 1 < Sc / 64) stage(cur ^ 1, kt + 1);

        // mask (log2 domain): QK^T accumulator init (free add)
        floatx4 mvl[4];
#pragma unroll
        for (int cb = 0; cb < 4; ++cb)
            mvl[cb] = *(const floatx4*)(mbase + kt * 64 + cb * 16 + lq * 4);

        // K fragments once per tile, swizzled reads (conflict-free)
        bf16x8 kf[4][2];
#pragma unroll
        for (int cb = 0; cb < 4; ++cb)
#pragma unroll
            for (int kh = 0; kh < 2; ++kh)
                kf[cb][kh] = *(const bf16x8*)&Ks[cur][cb * 16 + ln]
                                               [((kh * 4 + lq) ^ sw) << 3];

        // per q-block: S^T = K*Q^T + mask -> exp2 -> swizzled Pt write
#pragma unroll
        for (int qb = 0; qb < 4; ++qb) {
            floatx4 s[4];
#pragma unroll
            for (int cb = 0; cb < 4; ++cb) s[cb] = mvl[cb];
            __builtin_amdgcn_s_setprio(1);
#pragma unroll
            for (int kh = 0; kh < 2; ++kh)
#pragma unroll
                for (int cb = 0; cb < 4; ++cb)
                    s[cb] = MFMA16(kf[cb][kh], qf[qb][kh], s[cb]);
            __builtin_amdgcn_s_setprio(0);
            float ds = 0.f;
#pragma unroll
            for (int cb = 0; cb < 4; ++cb) {
                U64 pk;
#pragma unroll
                for (int r = 0; r < 4; ++r) {
                    const float e = __builtin_amdgcn_exp2f(s[cb][r]);
                    ds += e;
                    pk.h[r] = (bf16)e;
                }
                // logical granule cb*4+lq (8B) -> phys granule ^(pkey)
                *(intx2*)(PtW + (qb * 16 + ln) * 64
                              + (((cb * 4 + lq) ^ pkey) << 2)) = pk.i;
            }
            dacc[qb] += ds;
        }

        // V fragments once per tile, swizzled reads (conflict-free)
        bf16x8 vf[4][2];
#pragma unroll
        for (int db = 0; db < 4; ++db)
#pragma unroll
            for (int kh = 0; kh < 2; ++kh)
                vf[db][kh] = *(const bf16x8*)&Vs[cur][db * 16 + ln]
                                               [((kh * 4 + lq) ^ sw) << 3];

        // per q-block: O^T += V^T * P^T ; pf reads de-swizzle Pt
#pragma unroll
        for (int qb = 0; qb < 4; ++qb) {
            const bf16x8 pf0 = *(const bf16x8*)(PtW + (qb * 16 + ln) * 64
                                                    + (((2 * lq) ^ pkey) << 2));
            const bf16x8 pf1 = *(const bf16x8*)(PtW + (qb * 16 + ln) * 64
                                                    + (((8 + 2 * lq) ^ pkey) << 2));
            __builtin_amdgcn_s_setprio(1);
#pragma unroll
            for (int db = 0; db < 4; ++db) {
                o[qb][db] = MFMA16(vf[db][0], pf0, o[qb][db]);
                o[qb][db] = MFMA16(vf[db][1], pf1, o[qb][db]);
            }
            __builtin_amdgcn_s_setprio(0);
        }
        cur ^= 1;
    }

    // finish denominators (sum over the 4-lane stride-16 group), store ctx
#pragma unroll
    for (int qb = 0; qb < 4; ++qb) {
        float dsum = dacc[qb];
        dsum += __shfl_xor(dsum, 16, 64);
        dsum += __shfl_xor(dsum, 32, 64);
        const float li = 1.f / dsum;
        const int qg = q0 + qb * 16 + ln;
#pragma unroll
        for (int db = 0; db < 4; ++db) {
            U64 pk;
#pragma unroll
            for (int r = 0; r < 4; ++r) pk.h[r] = (bf16)(o[qb][db][r] * li);
            *(intx2*)&ctx[((size_t)b * Sc + qg) * Hc + h * HDc + db * 16 + lq * 4] = pk.i;
        }
    }
}

// ---------------------------------------------------------------------------
// LayerNorm; output dtype keyed off the inline per-block flag
// ---------------------------------------------------------------------------
__global__ __launch_bounds__(256)
void layernorm_k(const bf16* __restrict__ hbuf, const float* __restrict__ lw,
                 const float* __restrict__ lb, void* __restrict__ outp,
                 const void* __restrict__ xraw)
{
    __shared__ float wmx[4];
    __shared__ float ssum[4], ssq[4];
    const int fl = detect_flag_block(xraw, wmx);

    const int row = blockIdx.x;
    const int t = threadIdx.x;
    const bf16* hp = hbuf + (size_t)row * Hc;

    union { intx2 i2; bf16 e[4]; } pk;
    pk.i2 = *(const intx2*)(hp + t * 4);
    float v[4], sum = 0.f, sq = 0.f;
#pragma unroll
    for (int i = 0; i < 4; ++i) {
        v[i] = (float)pk.e[i];
        sum += v[i];
        sq  += v[i] * v[i];
    }
#pragma unroll
    for (int off = 1; off < 64; off <<= 1) {
        sum += __shfl_xor(sum, off, 64);
        sq  += __shfl_xor(sq,  off, 64);
    }
    const int w = t >> 6;
    if ((t & 63) == 0) { ssum[w] = sum; ssq[w] = sq; }
    __syncthreads();
    sum = ssum[0] + ssum[1] + ssum[2] + ssum[3];
    sq  = ssq[0]  + ssq[1]  + ssq[2]  + ssq[3];

    const float mean = sum * (1.f / (float)Hc);
    const float var  = sq * (1.f / (float)Hc) - mean * mean;
    const float rstd = rsqrtf(var + 1e-12f);

    float ov[4];
#pragma unroll
    for (int i = 0; i < 4; ++i) {
        const int c = t * 4 + i;
        ov[i] = lw[c] * (v[i] - mean) * rstd + lb[c];
    }
    if (fl) {
        float* of = (float*)outp + (size_t)row * Hc + t * 4;
#pragma unroll
        for (int i = 0; i < 4; ++i) of[i] = ov[i];
    } else {
        union { intx2 i2; bf16 e[4]; } po;
#pragma unroll
        for (int i = 0; i < 4; ++i) po.e[i] = (bf16)ov[i];
        *(intx2*)((bf16*)outp + (size_t)row * Hc + t * 4) = po.i2;
    }
}

// ---------------------------------------------------------------------------
extern "C" void kernel_launch(void* const* d_in, const int* in_sizes, int n_in,
                              void* d_out, int out_size, void* d_ws, size_t ws_size,
                              hipStream_t stream)
{
    const void* x    = d_in[0];
    const void* mask = d_in[1];
    const void* Wq   = d_in[2];
    const void* bq   = d_in[3];
    const void* Wk   = d_in[4];
    const void* bk   = d_in[5];
    const void* Wv   = d_in[6];
    const void* bv   = d_in[7];
    const void* Wo   = d_in[8];
    const void* bo   = d_in[9];
    const void* lnw  = d_in[10];
    const void* lnb  = d_in[11];

    char* ws = (char*)d_ws;
    const size_t MB = 1024 * 1024;
    float* maskf = (float*)(ws + 4096);
    float* bqf   = (float*)(ws + 64 * 1024);
    float* bkf   = bqf + Hc;
    float* bvf   = bkf + Hc;
    float* bof   = bvf + Hc;
    float* lnwf  = bof + Hc;
    float* lnbf  = lnwf + Hc;
    bf16* xb  = (bf16*)(ws + 1 * MB);    // 16 MB
    bf16* wqb = (bf16*)(ws + 17 * MB);   // 2 MB each, contiguous wq|wk|wv|wo
    bf16* wkb = (bf16*)(ws + 19 * MB);
    bf16* wvb = (bf16*)(ws + 21 * MB);
    bf16* wob = (bf16*)(ws + 23 * MB);
    bf16* qb  = (bf16*)(ws + 25 * MB);   // 16 MB
    bf16* kb  = (bf16*)(ws + 41 * MB);
    bf16* vtb = (bf16*)(ws + 57 * MB);   // V^T
    bf16* cb  = (bf16*)(ws + 73 * MB);   // ctx; high water 89 MB
    bf16* hb  = qb;                      // h reuses q (dead after attention)

    // one conversion dispatch: x | weights | mask+vectors (flag inline)
    conv_all_k<<<6153, 256, 0, stream>>>(x, Wq, Wk, Wv, Wo, mask,
                                         bq, bk, bv, bo, lnw, lnb,
                                         xb, wqb, maskf, bqf, bkf, bvf,
                                         bof, lnwf, lnbf);

    dim3 gqkv(Hc / 128, Mc / 128, 3);
    qkv_gemm<<<gqkv, 256, 0, stream>>>(xb, wqb, bqf, wkb, bkf, wvb, bvf, qb, kb, vtb);
    attention<<<dim3(Bc * NHc * (Sc / 256)), 256, 0, stream>>>(qb, kb, vtb, maskf, cb);
    oproj_gemm<<<dim3(Hc / 128, Mc / 128), 256, 0, stream>>>(cb, wob, bof, xb, hb);
    layernorm_k<<<dim3(Mc), 256, 0, stream>>>(hb, lnwf, lnbf, d_out, x);
}

// Round 9
// 287.653 us; speedup vs baseline: 1.1910x; 1.0018x over previous
//
#include <hip/hip_runtime.h>

typedef __bf16 bf16;
typedef __bf16 bf16x8 __attribute__((ext_vector_type(8)));
typedef __bf16 bf16x4 __attribute__((ext_vector_type(4)));
typedef float floatx4 __attribute__((ext_vector_type(4)));
typedef int   intx4  __attribute__((ext_vector_type(4)));
typedef int   intx2  __attribute__((ext_vector_type(2)));

#define MFMA16(a,b,c) __builtin_amdgcn_mfma_f32_16x16x32_bf16((a),(b),(c),0,0,0)

constexpr int Bc  = 4;
constexpr int Sc  = 2048;
constexpr int Hc  = 1024;
constexpr int NHc = 16;
constexpr int HDc = 64;
constexpr int Mc  = Bc * Sc;       // 8192 rows
constexpr int KIT = Hc / 32;       // 32 k-iterations
constexpr float L2E = 1.44269504088896f;

union U64  { bf16x4 h; intx2 i; };

// async global->LDS, 16B per lane (dest must be wave-uniform base + lane*16)
__device__ __forceinline__ void ld16(const bf16* g, bf16* l) {
    __builtin_amdgcn_global_load_lds(
        (const __attribute__((address_space(1))) void*)g,
        (__attribute__((address_space(3))) void*)l, 16, 0, 0);
}

// ---------------------------------------------------------------------------
// Inline per-block dtype detect: 256 threads read the first 256 ushorts of x
// (512B, L2-broadcast), treat each as truncated fp32, wave-parallel max.
// Semantics identical to the original serial loop. ~300 cy per block.
// ---------------------------------------------------------------------------
__device__ __forceinline__ int detect_flag_block(const void* x, float* wmx)
{
    const unsigned short* xs = (const unsigned short*)x;
    const int tt = threadIdx.x;            // 256 threads, one value each
    unsigned int bits = ((unsigned int)xs[tt]) << 16;
    float v = __uint_as_float(bits);
    float a = isfinite(v) ? fabsf(v) : 1e30f;
#pragma unroll
    for (int off = 1; off < 64; off <<= 1)
        a = fmaxf(a, __shfl_xor(a, off, 64));
    if ((tt & 63) == 0) wmx[tt >> 6] = a;
    __syncthreads();
    const float m = fmaxf(fmaxf(wmx[0], wmx[1]), fmaxf(wmx[2], wmx[3]));
    __syncthreads();                       // wmx reusable after this
    return (m > 1e6f) ? 1 : 0;
}

// ---------------------------------------------------------------------------
// One merged conversion kernel: x (1048576 g8) | 4 weights (524288 g8) |
// mask+6 vectors (1792 g8)
// ---------------------------------------------------------------------------
__global__ __launch_bounds__(256)
void conv_all_k(const void* __restrict__ x,
                const void* __restrict__ Wq, const void* __restrict__ Wk,
                const void* __restrict__ Wv, const void* __restrict__ Wo,
                const void* __restrict__ mask,
                const void* __restrict__ bq, const void* __restrict__ bk,
                const void* __restrict__ bv, const void* __restrict__ bo,
                const void* __restrict__ lnw, const void* __restrict__ lnb,
                bf16* __restrict__ xb, bf16* __restrict__ wdst,
                float* maskf, float* bqf, float* bkf, float* bvf,
                float* bof, float* lnwf, float* lnbf)
{
    __shared__ float wmx[4];
    const int fl = detect_flag_block(x, wmx);

    const int g = blockIdx.x * 256 + threadIdx.x;
    if (g < 1048576) {
        if (fl) {
            const float* s = (const float*)x + (size_t)g * 8;
            union { intx4 v; bf16 e[8]; } o;
#pragma unroll
            for (int j = 0; j < 8; ++j) o.e[j] = (bf16)s[j];
            *(intx4*)(xb + (size_t)g * 8) = o.v;
        } else {
            *(intx4*)(xb + (size_t)g * 8) = *((const intx4*)x + g);
        }
    } else if (g < 1048576 + 524288) {
        const int gw = g - 1048576;
        const int wsel = gw >> 17, go = gw & 131071;
        const void* s = (wsel == 0) ? Wq : (wsel == 1) ? Wk : (wsel == 2) ? Wv : Wo;
        if (fl) {
            const float* sp = (const float*)s + (size_t)go * 8;
            union { intx4 v; bf16 e[8]; } o;
#pragma unroll
            for (int j = 0; j < 8; ++j) o.e[j] = (bf16)sp[j];
            *(intx4*)(wdst + (size_t)gw * 8) = o.v;
        } else {
            *(intx4*)(wdst + (size_t)gw * 8) = *((const intx4*)s + go);
        }
    } else {
        const int gs = g - 1048576 - 524288;
        if (gs >= 1792) return;
        const void* src; float* dst; int off; float scl = 1.0f;
        if (gs < 1024) { src = mask; dst = maskf; off = gs * 8; scl = L2E; }
        else {
            const int a = (gs - 1024) >> 7;
            off = ((gs - 1024) & 127) * 8;
            switch (a) {
                case 0: src = bq;  dst = bqf;  break;
                case 1: src = bk;  dst = bkf;  break;
                case 2: src = bv;  dst = bvf;  break;
                case 3: src = bo;  dst = bof;  break;
                case 4: src = lnw; dst = lnwf; break;
                default: src = lnb; dst = lnbf; break;
            }
        }
        if (fl) {
            const float* s = (const float*)src + off;
#pragma unroll
            for (int j = 0; j < 8; ++j) dst[off + j] = s[j] * scl;
        } else {
            union { intx4 v; bf16 e[8]; } u;
            u.v = *(const intx4*)((const bf16*)src + off);
#pragma unroll
            for (int j = 0; j < 8; ++j) dst[off + j] = (float)u.e[j] * scl;
        }
    }
}

// ---------------------------------------------------------------------------
// GEMM core: 128x128 tile over K=1024, A/W row-major.
// 2-phase pipelined: double-buffered LDS, stage(kb+1) issued BEFORE
// ds_read+MFMA of kb, ONE barrier per K-step.
// SWAP=0: acc[i][j] = C[xrow-block i][feat-block j]
// SWAP=1: acc[i][j] = C[feat-block j][xrow-block i] (lane cols = xrow)
// ---------------------------------------------------------------------------
template<int SWAP>
__device__ __forceinline__
void gemm_core(const bf16* __restrict__ A, const bf16* __restrict__ W,
               int m0, int n0, int t, bf16* As, bf16* Bs, floatx4 (&acc)[4][4])
{
    const int l  = t & 63, w = t >> 6;
    const int wr = w >> 1, wc = w & 1;
    const int lq = l >> 4, ln = l & 15;
    const int srow = t >> 2;            // 0..63
    const int scol = (t & 3) * 8;       // 0,8,16,24

    const bf16* a0 = A + (size_t)(m0 + srow) * Hc + scol;
    const bf16* b0 = W + (size_t)(n0 + srow) * Hc + scol;
    const int dst = srow * 32 + scol;   // lane-linear within a tile buffer

    auto stage = [&](int buf, int kb) {
        const int off = kb * 32;
        bf16* dA = As + buf * 4096;
        bf16* dB = Bs + buf * 4096;
        ld16(a0 + off,           dA + dst);
        ld16(a0 + 64 * Hc + off, dA + 64 * 32 + dst);
        ld16(b0 + off,           dB + dst);
        ld16(b0 + 64 * Hc + off, dB + 64 * 32 + dst);
    };

    stage(0, 0);
    int cur = 0;
    for (int kb = 0; kb < KIT; ++kb) {
        __syncthreads();                 // buf[cur] ready; buf[cur^1] readers done
        if (kb + 1 < KIT) stage(cur ^ 1, kb + 1);

        const bf16* Ab = As + cur * 4096;
        const bf16* Bb = Bs + cur * 4096;
        bf16x8 af[4], bw[4];
#pragma unroll
        for (int i = 0; i < 4; ++i)
            af[i] = *(const bf16x8*)&Ab[(wr * 64 + i * 16 + ln) * 32 + lq * 8];
#pragma unroll
        for (int j = 0; j < 4; ++j)
            bw[j] = *(const bf16x8*)&Bb[(wc * 64 + j * 16 + ln) * 32 + lq * 8];

        __builtin_amdgcn_s_setprio(1);
#pragma unroll
        for (int i = 0; i < 4; ++i)
#pragma unroll
            for (int j = 0; j < 4; ++j)
                acc[i][j] = SWAP ? MFMA16(bw[j], af[i], acc[i][j])
                                 : MFMA16(af[i], bw[j], acc[i][j]);
        __builtin_amdgcn_s_setprio(0);
        cur ^= 1;
    }
}

// chunked XCD remap for a (8 x 64) tile grid: each XCD owns 8 contiguous
// row-panels -> A-panel L2-resident per XCD, W fully L2-resident. Bijective.
__device__ __forceinline__ void xcd_remap(int bx, int by, int& m0, int& n0)
{
    const int flat = by * 8 + bx;            // dispatch-linear id, 0..511
    const int sw   = (flat & 7) * 64 + (flat >> 3);
    m0 = (sw >> 3) * 128;
    n0 = (sw & 7) * 128;
}

// ---------------------------------------------------------------------------
// Fused QKV: z=0 -> q (scaled by 0.125*log2e) [B,NH,S,HD]; z=1 -> k;
// z=2 -> V^T [B,NH,HD,S] via LDS transpose
// launch_bounds(256,4): est. ~110 VGPR fits the 128 cap -> 4 blocks/CU
// (R8 proved the 2->3 step pays; one more step of TLP over the DMA drain).
// ---------------------------------------------------------------------------
__global__ __launch_bounds__(256, 4)
void qkv_gemm(const bf16* __restrict__ x,
              const bf16* __restrict__ Wq, const float* __restrict__ bq,
              const bf16* __restrict__ Wk, const float* __restrict__ bk,
              const bf16* __restrict__ Wv, const float* __restrict__ bv,
              bf16* __restrict__ qo, bf16* __restrict__ ko, bf16* __restrict__ vto)
{
    __shared__ __align__(16) bf16 smem[16384];  // 2 x (2x4096) dbuf; Ct reuse
    const int z = blockIdx.z;
    const bf16*  W    = (z == 0) ? Wq : (z == 1) ? Wk : Wv;
    const float* bias = (z == 0) ? bq : (z == 1) ? bk : bv;

    int m0, n0;
    xcd_remap(blockIdx.x, blockIdx.y, m0, n0);
    const int t  = threadIdx.x;
    const int l  = t & 63, w = t >> 6;
    const int wr = w >> 1, wc = w & 1;
    const int lq = l >> 4, ln = l & 15;

    if (z < 2) {
        floatx4 acc[4][4] = {};
        gemm_core<1>(x, W, m0, n0, t, smem, smem + 8192, acc);
        bf16* out = (z == 0) ? qo : ko;
        const float sc = (z == 0) ? 0.125f * L2E : 1.0f;
#pragma unroll
        for (int j = 0; j < 4; ++j) {
            const int feat = n0 + wc * 64 + j * 16 + lq * 4;   // 4 consecutive
            const floatx4 bb = *(const floatx4*)&bias[feat];
            const int hh = feat >> 6, dd = feat & 63;
#pragma unroll
            for (int i = 0; i < 4; ++i) {
                const int xrow = m0 + wr * 64 + i * 16 + ln;
                const int bi = xrow >> 11, si = xrow & (Sc - 1);
                U64 pk;
#pragma unroll
                for (int r = 0; r < 4; ++r) pk.h[r] = (bf16)((acc[i][j][r] + bb[r]) * sc);
                *(intx2*)&out[(((size_t)bi * NHc + hh) * Sc + si) * HDc + dd] = pk.i;
            }
        }
    } else {
        floatx4 acc[4][4] = {};
        gemm_core<0>(x, W, m0, n0, t, smem, smem + 8192, acc);
        // transpose epilogue: Ct[64 cols][136 rows], two col-halves
        bf16* Ct = smem;
        const int bi = m0 >> 11, s0 = m0 & (Sc - 1);
        for (int h2 = 0; h2 < 2; ++h2) {
            __syncthreads();
            if (wc == h2) {
#pragma unroll
                for (int j = 0; j < 4; ++j) {
                    const int c = j * 16 + ln;
                    const float bb = bias[n0 + h2 * 64 + c];
#pragma unroll
                    for (int i = 0; i < 4; ++i) {
                        U64 pk;
#pragma unroll
                        for (int r = 0; r < 4; ++r) pk.h[r] = (bf16)(acc[i][j][r] + bb);
                        *(intx2*)&Ct[c * 136 + wr * 64 + i * 16 + lq * 4] = pk.i;
                    }
                }
            }
            __syncthreads();
#pragma unroll
            for (int u = 0; u < 4; ++u) {
                const int id = t + 256 * u;           // 0..1023
                const int c = id >> 4, rg = id & 15;
                const int hh = (n0 >> 6) + h2;
                intx4 val = *(const intx4*)&Ct[c * 136 + rg * 8];
                *(intx4*)&vto[(((size_t)bi * NHc + hh) * HDc + c) * Sc + s0 + rg * 8] = val;
            }
        }
    }
}

// ---------------------------------------------------------------------------
// Output projection + bias + residual -> h (bf16), b64 loads/stores
// ---------------------------------------------------------------------------
__global__ __launch_bounds__(256, 4)
void oproj_gemm(const bf16* __restrict__ ctx, const bf16* __restrict__ Wo,
                const float* __restrict__ bo, const bf16* __restrict__ xb,
                bf16* __restrict__ hout)
{
    __shared__ __align__(16) bf16 smem[16384];
    int m0, n0;
    xcd_remap(blockIdx.x, blockIdx.y, m0, n0);
    const int t  = threadIdx.x;
    floatx4 acc[4][4] = {};
    gemm_core<1>(ctx, Wo, m0, n0, t, smem, smem + 8192, acc);

    const int l  = t & 63, w = t >> 6;
    const int wr = w >> 1, wc = w & 1;
    const int lq = l >> 4, ln = l & 15;
#pragma unroll
    for (int j = 0; j < 4; ++j) {
        const int col = n0 + wc * 64 + j * 16 + lq * 4;   // 4 consecutive
        const floatx4 bb = *(const floatx4*)&bo[col];
#pragma unroll
        for (int i = 0; i < 4; ++i) {
            const int row = m0 + wr * 64 + i * 16 + ln;
            U64 rx;
            rx.i = *(const intx2*)&xb[(size_t)row * Hc + col];
            U64 pk;
#pragma unroll
            for (int r = 0; r < 4; ++r)
                pk.h[r] = (bf16)(acc[i][j][r] + bb[r] + (float)rx.h[r]);
            *(intx2*)&hout[(size_t)row * Hc + col] = pk.i;
        }
    }
}

// ---------------------------------------------------------------------------
// Flash attention, S^T formulation, fixed-max softmax. R7 structure with the
// denominator moved back to ones-MFMA (R0-verified): removes the 64 serial
// f32 adds/tile from the critical VALU pipe (+8 MFMA on the lighter matrix
// pipe) and drops the epilogue shuffles.
// ---------------------------------------------------------------------------
__global__ __launch_bounds__(256, 2)
void attention(const bf16* __restrict__ q, const bf16* __restrict__ k,
               const bf16* __restrict__ vt, const float* __restrict__ maskf,
               bf16* __restrict__ ctx)
{
    __shared__ __align__(16) bf16 Ks[2][64][64];   // [dbuf][kpos][hd] swizzled
    __shared__ __align__(16) bf16 Vs[2][64][64];   // [dbuf][d][kpos] swizzled
    __shared__ __align__(16) bf16 Pt[4][64][64];   // [wave][qrow][kpos] swizzled

    // XCD-aware remap: raw%8 = XCD; 8 consecutive (b,h) per XCD. 512%8==0.
    const int raw = blockIdx.x;                 // 0..511
    const int xcd = raw & 7, jj = raw >> 3;     // jj 0..63
    const int bh  = xcd * 8 + (jj >> 3);
    const int qt  = jj & 7;                     // q-tile of 256 rows
    const int b = bh >> 4, h = bh & 15;
    const int t = threadIdx.x, w = t >> 6, l = t & 63;
    const int lq = l >> 4, ln = l & 15;
    const int q0 = qt * 256 + w * 64;

    const bf16* kg = k  + (size_t)bh * Sc * HDc;
    const bf16* vg = vt + (size_t)bh * HDc * Sc;
    const float* mbase = maskf + b * Sc;        // pre-scaled by log2e

    // DMA staging geometry: wave w covers rows [16w,16w+16) in two 8-row
    // calls; dest lane-linear; LDS granule c of row r holds global granule
    // c^(r&7) via pre-swizzled global source column.
    const int rr  = l >> 3;
    const int gsw = ((l & 7) ^ rr) << 3;        // pre-swizzled global col (elems)
    const int r0  = w * 16 + rr, r1 = r0 + 8;
    const int dco = (l & 7) << 3;               // lane-linear LDS col (elems)
    const int sw  = ln & 7;                     // K/V read-side swizzle key
    const int pkey = sw << 1;                   // Pt granule XOR key (even)

    // Q fragments in registers (B-operand); q pre-scaled by 0.125*log2e
    bf16x8 qf[4][2];
#pragma unroll
    for (int qb = 0; qb < 4; ++qb)
#pragma unroll
        for (int kh = 0; kh < 2; ++kh)
            qf[qb][kh] = *(const bf16x8*)(q + ((size_t)bh * Sc + q0 + qb * 16 + ln) * HDc
                                            + kh * 32 + lq * 8);

    bf16x8 ones8;
#pragma unroll
    for (int jj2 = 0; jj2 < 8; ++jj2) ones8[jj2] = (bf16)1.0f;

    floatx4 o[4][4] = {};
    floatx4 accl[4] = {};

    auto stage = [&](int buf, int kt) {
        bf16* Kd = &Ks[buf][0][0];
        bf16* Vd = &Vs[buf][0][0];
        ld16(kg + (size_t)(kt * 64 + r0) * HDc + gsw, Kd + r0 * 64 + dco);
        ld16(kg + (size_t)(kt * 64 + r1) * HDc + gsw, Kd + r1 * 64 + dco);
        ld16(vg + (size_t)r0 * Sc + kt * 64 + gsw,    Vd + r0 * 64 + dco);
        ld16(vg + (size_t)r1 * Sc + kt * 64 + gsw,    Vd + r1 * 64 + dco);
    };

    stage(0, 0);
    int cur = 0;
    bf16* PtW = &Pt[w][0][0];                   // wave-private rows

    for (int kt = 0; kt < Sc / 64; ++kt) {
        __syncthreads();                 // drains own vmcnt -> buf[cur] ready
        if (kt + 1 < Sc / 64) stage(cur ^ 1, kt + 1);

        // mask (log2 domain): QK^T accumulator init (free add)
        floatx4 mvl[4];
#pragma unroll
        for (int cb = 0; cb < 4; ++cb)
            mvl[cb] = *(const floatx4*)(mbase + kt * 64 + cb * 16 + lq * 4);

        // K fragments once per tile, swizzled reads (conflict-free)
        bf16x8 kf[4][2];
#pragma unroll
        for (int cb = 0; cb < 4; ++cb)
#pragma unroll
            for (int kh = 0; kh < 2; ++kh)
                kf[cb][kh] = *(const bf16x8*)&Ks[cur][cb * 16 + ln]
                                               [((kh * 4 + lq) ^ sw) << 3];

        // per q-block: S^T = K*Q^T + mask -> exp2 -> swizzled Pt write
#pragma unroll
        for (int qb = 0; qb < 4; ++qb) {
            floatx4 s[4];
#pragma unroll
            for (int cb = 0; cb < 4; ++cb) s[cb] = mvl[cb];
            __builtin_amdgcn_s_setprio(1);
#pragma unroll
            for (int kh = 0; kh < 2; ++kh)
#pragma unroll
                for (int cb = 0; cb < 4; ++cb)
                    s[cb] = MFMA16(kf[cb][kh], qf[qb][kh], s[cb]);
            __builtin_amdgcn_s_setprio(0);
#pragma unroll
            for (int cb = 0; cb < 4; ++cb) {
                U64 pk;
#pragma unroll
                for (int r = 0; r < 4; ++r)
                    pk.h[r] = (bf16)__builtin_amdgcn_exp2f(s[cb][r]);
                // logical granule cb*4+lq (8B) -> phys granule ^(pkey)
                *(intx2*)(PtW + (qb * 16 + ln) * 64
                              + (((cb * 4 + lq) ^ pkey) << 2)) = pk.i;
            }
        }

        // V fragments once per tile, swizzled reads (conflict-free)
        bf16x8 vf[4][2];
#pragma unroll
        for (int db = 0; db < 4; ++db)
#pragma unroll
            for (int kh = 0; kh < 2; ++kh)
                vf[db][kh] = *(const bf16x8*)&Vs[cur][db * 16 + ln]
                                               [((kh * 4 + lq) ^ sw) << 3];

        // per q-block: O^T += V^T * P^T ; l += ones*P^T ; pf de-swizzles Pt
#pragma unroll
        for (int qb = 0; qb < 4; ++qb) {
            const bf16x8 pf0 = *(const bf16x8*)(PtW + (qb * 16 + ln) * 64
                                                    + (((2 * lq) ^ pkey) << 2));
            const bf16x8 pf1 = *(const bf16x8*)(PtW + (qb * 16 + ln) * 64
                                                    + (((8 + 2 * lq) ^ pkey) << 2));
            __builtin_amdgcn_s_setprio(1);
#pragma unroll
            for (int db = 0; db < 4; ++db) {
                o[qb][db] = MFMA16(vf[db][0], pf0, o[qb][db]);
                o[qb][db] = MFMA16(vf[db][1], pf1, o[qb][db]);
            }
            accl[qb] = MFMA16(ones8, pf0, accl[qb]);
            accl[qb] = MFMA16(ones8, pf1, accl[qb]);
            __builtin_amdgcn_s_setprio(0);
        }
        cur ^= 1;
    }

    // normalize + store ctx [B,S,H] (accl[qb][0] = full row denom)
#pragma unroll
    for (int qb = 0; qb < 4; ++qb) {
        const float li = 1.f / accl[qb][0];
        const int qg = q0 + qb * 16 + ln;
#pragma unroll
        for (int db = 0; db < 4; ++db) {
            U64 pk;
#pragma unroll
            for (int r = 0; r < 4; ++r) pk.h[r] = (bf16)(o[qb][db][r] * li);
            *(intx2*)&ctx[((size_t)b * Sc + qg) * Hc + h * HDc + db * 16 + lq * 4] = pk.i;
        }
    }
}

// ---------------------------------------------------------------------------
// LayerNorm; output dtype keyed off the inline per-block flag
// ---------------------------------------------------------------------------
__global__ __launch_bounds__(256)
void layernorm_k(const bf16* __restrict__ hbuf, const float* __restrict__ lw,
                 const float* __restrict__ lb, void* __restrict__ outp,
                 const void* __restrict__ xraw)
{
    __shared__ float wmx[4];
    __shared__ float ssum[4], ssq[4];
    const int fl = detect_flag_block(xraw, wmx);

    const int row = blockIdx.x;
    const int t = threadIdx.x;
    const bf16* hp = hbuf + (size_t)row * Hc;

    union { intx2 i2; bf16 e[4]; } pk;
    pk.i2 = *(const intx2*)(hp + t * 4);
    float v[4], sum = 0.f, sq = 0.f;
#pragma unroll
    for (int i = 0; i < 4; ++i) {
        v[i] = (float)pk.e[i];
        sum += v[i];
        sq  += v[i] * v[i];
    }
#pragma unroll
    for (int off = 1; off < 64; off <<= 1) {
        sum += __shfl_xor(sum, off, 64);
        sq  += __shfl_xor(sq,  off, 64);
    }
    const int w = t >> 6;
    if ((t & 63) == 0) { ssum[w] = sum; ssq[w] = sq; }
    __syncthreads();
    sum = ssum[0] + ssum[1] + ssum[2] + ssum[3];
    sq  = ssq[0]  + ssq[1]  + ssq[2]  + ssq[3];

    const float mean = sum * (1.f / (float)Hc);
    const float var  = sq * (1.f / (float)Hc) - mean * mean;
    const float rstd = rsqrtf(var + 1e-12f);

    float ov[4];
#pragma unroll
    for (int i = 0; i < 4; ++i) {
        const int c = t * 4 + i;
        ov[i] = lw[c] * (v[i] - mean) * rstd + lb[c];
    }
    if (fl) {
        float* of = (float*)outp + (size_t)row * Hc + t * 4;
#pragma unroll
        for (int i = 0; i < 4; ++i) of[i] = ov[i];
    } else {
        union { intx2 i2; bf16 e[4]; } po;
#pragma unroll
        for (int i = 0; i < 4; ++i) po.e[i] = (bf16)ov[i];
        *(intx2*)((bf16*)outp + (size_t)row * Hc + t * 4) = po.i2;
    }
}

// ---------------------------------------------------------------------------
extern "C" void kernel_launch(void* const* d_in, const int* in_sizes, int n_in,
                              void* d_out, int out_size, void* d_ws, size_t ws_size,
                              hipStream_t stream)
{
    const void* x    = d_in[0];
    const void* mask = d_in[1];
    const void* Wq   = d_in[2];
    const void* bq   = d_in[3];
    const void* Wk   = d_in[4];
    const void* bk   = d_in[5];
    const void* Wv   = d_in[6];
    const void* bv   = d_in[7];
    const void* Wo   = d_in[8];
    const void* bo   = d_in[9];
    const void* lnw  = d_in[10];
    const void* lnb  = d_in[11];

    char* ws = (char*)d_ws;
    const size_t MB = 1024 * 1024;
    float* maskf = (float*)(ws + 4096);
    float* bqf   = (float*)(ws + 64 * 1024);
    float* bkf   = bqf + Hc;
    float* bvf   = bkf + Hc;
    float* bof   = bvf + Hc;
    float* lnwf  = bof + Hc;
    float* lnbf  = lnwf + Hc;
    bf16* xb  = (bf16*)(ws + 1 * MB);    // 16 MB
    bf16* wqb = (bf16*)(ws + 17 * MB);   // 2 MB each, contiguous wq|wk|wv|wo
    bf16* wkb = (bf16*)(ws + 19 * MB);
    bf16* wvb = (bf16*)(ws + 21 * MB);
    bf16* wob = (bf16*)(ws + 23 * MB);
    bf16* qb  = (bf16*)(ws + 25 * MB);   // 16 MB
    bf16* kb  = (bf16*)(ws + 41 * MB);
    bf16* vtb = (bf16*)(ws + 57 * MB);   // V^T
    bf16* cb  = (bf16*)(ws + 73 * MB);   // ctx; high water 89 MB
    bf16* hb  = qb;                      // h reuses q (dead after attention)

    // one conversion dispatch: x | weights | mask+vectors (flag inline)
    conv_all_k<<<6153, 256, 0, stream>>>(x, Wq, Wk, Wv, Wo, mask,
                                         bq, bk, bv, bo, lnw, lnb,
                                         xb, wqb, maskf, bqf, bkf, bvf,
                                         bof, lnwf, lnbf);

    dim3 gqkv(Hc / 128, Mc / 128, 3);
    qkv_gemm<<<gqkv, 256, 0, stream>>>(xb, wqb, bqf, wkb, bkf, wvb, bvf, qb, kb, vtb);
    attention<<<dim3(Bc * NHc * (Sc / 256)), 256, 0, stream>>>(qb, kb, vtb, maskf, cb);
    oproj_gemm<<<dim3(Hc / 128, Mc / 128), 256, 0, stream>>>(cb, wob, bof, xb, hb);
    layernorm_k<<<dim3(Mc), 256, 0, stream>>>(hb, lnwf, lnbf, d_out, x);
}